// Round 2
// baseline (4273.050 us; speedup 1.0000x reference)
//
#include <hip/hip_runtime.h>

typedef __attribute__((ext_vector_type(8))) unsigned short us8;

constexpr int kNC = 100000;
constexpr int kNP = 50000;
constexpr int kNT = kNC + kNP;
constexpr int kE1 = 300000;
constexpr int kE2 = 300000;

__device__ __forceinline__ float geluf(float x) {
    return 0.5f * x * (1.0f + erff(x * 0.7071067811865475f));
}
// monotone float<->uint encoding so atomicMax(uint) == max(float)
__device__ __forceinline__ unsigned int encodeF(float f) {
    unsigned int u = __float_as_uint(f);
    return (u & 0x80000000u) ? ~u : (u | 0x80000000u);
}
__device__ __forceinline__ float decodeF(unsigned int u) {
    return __uint_as_float((u & 0x80000000u) ? (u & 0x7fffffffu) : ~u);
}
__device__ __forceinline__ unsigned short f2bf(float f) {  // RTNE
    unsigned int u = __float_as_uint(f);
    u += 0x7fffu + ((u >> 16) & 1u);
    return (unsigned short)(u >> 16);
}
__device__ __forceinline__ float bf2f(unsigned short s) {
    return __uint_as_float(((unsigned int)s) << 16);
}

// weff[:,0:128] = w_k @ blockdiag(a); [:,128:256] = w_q; [:,256:384] = w_v @ blockdiag(m)
__global__ void fold_k(const float* __restrict__ w, const float* __restrict__ b,
                       const float* __restrict__ ar, const float* __restrict__ mr,
                       float* __restrict__ weff, float* __restrict__ beff) {
    int col = blockIdx.x;   // 0..383
    int i = threadIdx.x;    // 0..127
    float acc, bacc;
    if (col >= 128 && col < 256) {
        acc = w[i * 384 + col];
        bacc = b[col];
    } else {
        const float* rel = (col < 128) ? ar : mr;
        int base = (col < 128) ? 0 : 256;
        int c = col - base;
        int h = c >> 6, j = c & 63;
        acc = 0.0f; bacc = 0.0f;
        for (int d = 0; d < 64; ++d) {
            float rv = rel[(h * 64 + d) * 64 + j];
            acc  = fmaf(w[i * 384 + base + h * 64 + d], rv, acc);
            bacc = fmaf(b[base + h * 64 + d], rv, bacc);
        }
    }
    weff[i * 384 + col] = acc;
    if (i == 0) beff[col] = bacc;
}

// C[M,128] = op(A[M,128]) @ W[128 x 128 window] + bias.  K=128 fixed.
// W/bias are pre-offset to the column window; W row stride = ldb.
// PRO: gelu on A.  EPI: out = g*o + (1-g)*Xres, g=sigmoid(*sgate); RELU optional.
// BF16OUT: store bf16 (plain epilogue only).
template<int PRO, int EPI, int RELU, int BF16OUT>
__global__ __launch_bounds__(256) void gemm128(
    const float* __restrict__ A,
    const float* __restrict__ W, int ldb,
    const float* __restrict__ bias,
    void* __restrict__ Cv,
    int M,
    const float* __restrict__ Xres,
    const float* __restrict__ sgate)
{
    __shared__ float As[128][132];   // [k][row], padded
    __shared__ float Ws[128][128];   // [k][col]
    const int t = threadIdx.x;
    const int row0 = blockIdx.x * 128;

    { // A tile transposed into LDS
        int rl = t & 31;
        int kh = t >> 5;  // 0..7
        #pragma unroll
        for (int ir = 0; ir < 4; ++ir) {
            int r = ir * 32 + rl;
            int gr = row0 + r;
            #pragma unroll
            for (int ic = 0; ic < 4; ++ic) {
                int k = (ic * 8 + kh) * 4;
                float4 v = make_float4(0.f, 0.f, 0.f, 0.f);
                if (gr < M) v = *(const float4*)(A + (size_t)gr * 128 + k);
                if (PRO) { v.x = geluf(v.x); v.y = geluf(v.y); v.z = geluf(v.z); v.w = geluf(v.w); }
                As[k + 0][r] = v.x;
                As[k + 1][r] = v.y;
                As[k + 2][r] = v.z;
                As[k + 3][r] = v.w;
            }
        }
    }
    { // W tile
        int c = (t & 31) * 4;
        int kh = t >> 5;
        #pragma unroll
        for (int i = 0; i < 16; ++i) {
            int k = i * 8 + kh;
            *(float4*)&Ws[k][c] = *(const float4*)(W + (size_t)k * ldb + c);
        }
    }
    __syncthreads();

    const int tx = t & 15, ty = t >> 4;
    float acc[8][8];
    #pragma unroll
    for (int j = 0; j < 8; ++j) {
        float bv = bias[tx * 8 + j];
        #pragma unroll
        for (int i = 0; i < 8; ++i) acc[i][j] = bv;
    }

    #pragma unroll 4
    for (int k = 0; k < 128; ++k) {
        float a[8], w[8];
        *(float4*)&a[0] = *(const float4*)&As[k][ty * 8 + 0];
        *(float4*)&a[4] = *(const float4*)&As[k][ty * 8 + 4];
        *(float4*)&w[0] = *(const float4*)&Ws[k][tx * 8 + 0];
        *(float4*)&w[4] = *(const float4*)&Ws[k][tx * 8 + 4];
        #pragma unroll
        for (int i = 0; i < 8; ++i)
            #pragma unroll
            for (int j = 0; j < 8; ++j)
                acc[i][j] = fmaf(a[i], w[j], acc[i][j]);
    }

    float g = 0.f, omg = 0.f;
    if (EPI == 1) { g = 1.0f / (1.0f + expf(-sgate[0])); omg = 1.0f - g; }

    #pragma unroll
    for (int i = 0; i < 8; ++i) {
        int gr = row0 + ty * 8 + i;
        if (gr >= M) continue;
        if (BF16OUT) {
            us8 o;
            #pragma unroll
            for (int j = 0; j < 8; ++j) o[j] = f2bf(acc[i][j]);
            *(us8*)((unsigned short*)Cv + (size_t)gr * 128 + tx * 8) = o;
        } else {
            float o[8];
            #pragma unroll
            for (int j = 0; j < 8; ++j) {
                float v = acc[i][j];
                if (EPI == 1) {
                    float xv = Xres[(size_t)gr * 128 + tx * 8 + j];
                    v = g * v + omg * xv;
                    if (RELU) v = fmaxf(v, 0.0f);
                }
                o[j] = v;
            }
            *(float4*)((float*)Cv + (size_t)gr * 128 + tx * 8 + 0) = *(float4*)&o[0];
            *(float4*)((float*)Cv + (size_t)gr * 128 + tx * 8 + 4) = *(float4*)&o[4];
        }
    }
}

// 16 lanes per edge; lanes 0..7 = head0, 8..15 = head1. k bf16, q f32.
__global__ __launch_bounds__(256) void edge_logits(
    const int* __restrict__ src, const int* __restrict__ dst, int E,
    const unsigned short* __restrict__ kSrc, const float* __restrict__ qDst,
    int dstOff, const float* __restrict__ prel,
    float* __restrict__ alpha, unsigned int* __restrict__ mEnc)
{
    int gid = blockIdx.x * 256 + threadIdx.x;
    int e = gid >> 4;
    int lane = gid & 15;
    if (e >= E) return;
    int s = src[e], d = dst[e];
    us8 kv = *(const us8*)(kSrc + (size_t)s * 128 + lane * 8);
    float4 q0 = *(const float4*)(qDst + (size_t)d * 128 + lane * 8);
    float4 q1 = *(const float4*)(qDst + (size_t)d * 128 + lane * 8 + 4);
    float p = q0.x * bf2f(kv[0]) + q0.y * bf2f(kv[1]) + q0.z * bf2f(kv[2]) + q0.w * bf2f(kv[3])
            + q1.x * bf2f(kv[4]) + q1.y * bf2f(kv[5]) + q1.z * bf2f(kv[6]) + q1.w * bf2f(kv[7]);
    p += __shfl_xor(p, 1);
    p += __shfl_xor(p, 2);
    p += __shfl_xor(p, 4);
    if ((lane & 7) == 0) {
        int h = lane >> 3;
        float lg = p * prel[h] * 0.125f;   // / sqrt(64)
        alpha[(size_t)e * 2 + h] = lg;
        atomicMax(&mEnc[(size_t)(dstOff + d) * 2 + h], encodeF(lg));
    }
}

__global__ __launch_bounds__(256) void edge_expsum(
    const int* __restrict__ dst, int E, int dstOff,
    const unsigned int* __restrict__ mEnc, float* __restrict__ alpha,
    float* __restrict__ sSum)
{
    int e = blockIdx.x * 256 + threadIdx.x;
    if (e >= E) return;
    int d = dstOff + dst[e];
    float m0 = decodeF(mEnc[(size_t)d * 2 + 0]);
    float m1 = decodeF(mEnc[(size_t)d * 2 + 1]);
    float e0 = expf(alpha[(size_t)e * 2 + 0] - m0);
    float e1 = expf(alpha[(size_t)e * 2 + 1] - m1);
    alpha[(size_t)e * 2 + 0] = e0;
    alpha[(size_t)e * 2 + 1] = e1;
    atomicAdd(&sSum[(size_t)d * 2 + 0], e0);
    atomicAdd(&sSum[(size_t)d * 2 + 1], e1);
}

__global__ __launch_bounds__(256) void edge_scatter(
    const int* __restrict__ src, const int* __restrict__ dst, int E,
    const unsigned short* __restrict__ vSrc, int dstOff,
    const float* __restrict__ alpha, const float* __restrict__ sSum,
    float* __restrict__ outn)
{
    int gid = blockIdx.x * 256 + threadIdx.x;
    int e = gid >> 4;
    int lane = gid & 15;
    if (e >= E) return;
    int s = src[e], d = dstOff + dst[e];
    int h = lane >> 3;
    float w = alpha[(size_t)e * 2 + h] / (sSum[(size_t)d * 2 + h] + 1e-16f);
    us8 vv = *(const us8*)(vSrc + (size_t)s * 128 + lane * 8);
    float* o = outn + (size_t)d * 128 + lane * 8;
    #pragma unroll
    for (int j = 0; j < 8; ++j) atomicAdd(o + j, w * bf2f(vv[j]));
}

// out[M,16] = A[M,128] @ W[128,16] + bias
__global__ __launch_bounds__(256) void final16(
    const float* __restrict__ A, const float* __restrict__ W,
    const float* __restrict__ bias, float* __restrict__ out, int M)
{
    __shared__ float Ws[128 * 16];
    __shared__ float As[64][132];
    int t = threadIdx.x;
    int row0 = blockIdx.x * 64;
    for (int i = t * 4; i < 2048; i += 1024)
        *(float4*)&Ws[i] = *(const float4*)&W[i];
    {
        int rl = t >> 3;   // 0..31
        int cc = t & 7;    // 0..7
        for (int ir = 0; ir < 2; ++ir) {
            int r = ir * 32 + rl;
            int gr = row0 + r;
            for (int ic = 0; ic < 4; ++ic) {
                int c = (ic * 8 + cc) * 4;
                float4 v = make_float4(0.f, 0.f, 0.f, 0.f);
                if (gr < M) v = *(const float4*)(A + (size_t)gr * 128 + c);
                *(float4*)&As[r][c] = v;
            }
        }
    }
    __syncthreads();
    int r = t >> 2, q = t & 3;
    int gr = row0 + r;
    float acc[4];
    #pragma unroll
    for (int j = 0; j < 4; ++j) acc[j] = bias[q * 4 + j];
    for (int k = 0; k < 128; ++k) {
        float a = As[r][k];
        float4 w = *(const float4*)&Ws[k * 16 + q * 4];
        acc[0] = fmaf(a, w.x, acc[0]);
        acc[1] = fmaf(a, w.y, acc[1]);
        acc[2] = fmaf(a, w.z, acc[2]);
        acc[3] = fmaf(a, w.w, acc[3]);
    }
    if (gr < M) *(float4*)(out + (size_t)gr * 16 + q * 4) = *(float4*)&acc[0];
}

extern "C" void kernel_launch(void* const* d_in, const int* in_sizes, int n_in,
                              void* d_out, int out_size, void* d_ws, size_t ws_size,
                              hipStream_t stream)
{
    const float* xc  = (const float*)d_in[0];
    const float* xp  = (const float*)d_in[1];
    const float* w1c = (const float*)d_in[2];
    const float* b1c = (const float*)d_in[3];
    const float* w1p = (const float*)d_in[4];
    const float* b1p = (const float*)d_in[5];
    const float* a1cp= (const float*)d_in[6];
    const float* m1cp= (const float*)d_in[7];
    const float* p1cp= (const float*)d_in[8];
    const float* a1pc= (const float*)d_in[9];
    const float* m1pc= (const float*)d_in[10];
    const float* p1pc= (const float*)d_in[11];
    const float* ow1c= (const float*)d_in[12];
    const float* ob1c= (const float*)d_in[13];
    const float* ow1p= (const float*)d_in[14];
    const float* ob1p= (const float*)d_in[15];
    const float* s1c = (const float*)d_in[16];
    const float* s1p = (const float*)d_in[17];
    const float* w2c = (const float*)d_in[18];
    const float* b2c = (const float*)d_in[19];
    const float* w2p = (const float*)d_in[20];
    const float* b2p = (const float*)d_in[21];
    const float* a2pc= (const float*)d_in[25];
    const float* m2pc= (const float*)d_in[26];
    const float* p2pc= (const float*)d_in[27];
    const float* ow2c= (const float*)d_in[28];
    const float* ob2c= (const float*)d_in[29];
    const float* s2c = (const float*)d_in[32];
    const float* wl  = (const float*)d_in[34];
    const float* bl  = (const float*)d_in[35];
    const int* ecp_s = (const int*)d_in[36];
    const int* ecp_d = (const int*)d_in[37];
    const int* epc_s = (const int*)d_in[38];
    const int* epc_d = (const int*)d_in[39];
    float* outF = (float*)d_out;
    (void)in_sizes; (void)n_in; (void)out_size; (void)ws_size;

    // ---- static workspace layout (~238.0 MB total) ----
    char* ws = (char*)d_ws;
    const size_t B_kC   = 0;                                  // bf16 [NC,128]
    const size_t B_vC   = B_kC   + (size_t)kNC * 128 * 2;     // bf16 [NC,128]
    const size_t B_qC   = B_vC   + (size_t)kNC * 128 * 2;     // f32  [NC,128]
    const size_t B_kP   = B_qC   + (size_t)kNC * 128 * 4;     // bf16 [NP,128]
    const size_t B_vP   = B_kP   + (size_t)kNP * 128 * 2;     // bf16 [NP,128]
    const size_t B_qP   = B_vP   + (size_t)kNP * 128 * 2;     // f32  [NP,128]
    const size_t B_outn = B_qP   + (size_t)kNP * 128 * 4;     // f32  [NT,128]
    const size_t B_alph = B_outn + (size_t)kNT * 128 * 4;
    const size_t B_mEnc = B_alph + (size_t)(kE1 + kE2) * 2 * 4;
    const size_t B_sSum = B_mEnc + (size_t)kNT * 2 * 4;
    const size_t B_wec  = B_sSum + (size_t)kNT * 2 * 4;
    const size_t B_bec  = B_wec  + (size_t)128 * 384 * 4;
    const size_t B_wep  = B_bec  + (size_t)384 * 4;
    const size_t B_bep  = B_wep  + (size_t)128 * 384 * 4;

    unsigned short* kC = (unsigned short*)(ws + B_kC);
    unsigned short* vC = (unsigned short*)(ws + B_vC);
    float*          qC = (float*)(ws + B_qC);
    unsigned short* kP = (unsigned short*)(ws + B_kP);
    unsigned short* vP = (unsigned short*)(ws + B_vP);
    float*          qP = (float*)(ws + B_qP);
    float*        outn = (float*)(ws + B_outn);
    float*       alpha = (float*)(ws + B_alph);
    unsigned int* mEnc = (unsigned int*)(ws + B_mEnc);
    float*        sSum = (float*)(ws + B_sSum);
    float*         wec = (float*)(ws + B_wec);
    float*         bec = (float*)(ws + B_bec);
    float*         wep = (float*)(ws + B_wep);
    float*         bep = (float*)(ws + B_bep);
    // phase-lifetime aliases (regions dead by the time these are written):
    float*          hc = (float*)(ws + 0);                                  // [NC,128] f32 over kC+vC
    float*          hp = (float*)(ws + (size_t)kNC * 128 * 4);              // [NP,128] f32 over qC head
    float*         qC2 = (float*)(ws + (size_t)(kNC + kNP) * 128 * 4);      // [NC,128] f32 over qC tail+kP+vP
    unsigned short* kP2 = (unsigned short*)(ws + B_outn + (size_t)kNC * 128 * 4);
    unsigned short* vP2 = (unsigned short*)(ws + B_outn + (size_t)kNC * 128 * 4 + (size_t)kNP * 128 * 2);

    auto cdiv = [](int a, int b) { return (a + b - 1) / b; };
    dim3 blk(256);
    const float* nullF = nullptr;

    // ================= layer 1 =================
    hipLaunchKernelGGL(fold_k, dim3(384), dim3(128), 0, stream, w1c, b1c, a1cp, m1cp, wec, bec);
    hipLaunchKernelGGL(fold_k, dim3(384), dim3(128), 0, stream, w1p, b1p, a1pc, m1pc, wep, bep);
    hipLaunchKernelGGL((gemm128<0,0,0,1>), dim3(cdiv(kNC,128)), blk, 0, stream,
                       xc, wec + 0,   384, bec + 0,   (void*)kC, kNC, nullF, nullF);
    hipLaunchKernelGGL((gemm128<0,0,0,0>), dim3(cdiv(kNC,128)), blk, 0, stream,
                       xc, wec + 128, 384, bec + 128, (void*)qC, kNC, nullF, nullF);
    hipLaunchKernelGGL((gemm128<0,0,0,1>), dim3(cdiv(kNC,128)), blk, 0, stream,
                       xc, wec + 256, 384, bec + 256, (void*)vC, kNC, nullF, nullF);
    hipLaunchKernelGGL((gemm128<0,0,0,1>), dim3(cdiv(kNP,128)), blk, 0, stream,
                       xp, wep + 0,   384, bep + 0,   (void*)kP, kNP, nullF, nullF);
    hipLaunchKernelGGL((gemm128<0,0,0,0>), dim3(cdiv(kNP,128)), blk, 0, stream,
                       xp, wep + 128, 384, bep + 128, (void*)qP, kNP, nullF, nullF);
    hipLaunchKernelGGL((gemm128<0,0,0,1>), dim3(cdiv(kNP,128)), blk, 0, stream,
                       xp, wep + 256, 384, bep + 256, (void*)vP, kNP, nullF, nullF);
    hipMemsetAsync(mEnc, 0, (size_t)kNT * 2 * 4, stream);
    hipMemsetAsync(sSum, 0, (size_t)kNT * 2 * 4, stream);
    hipMemsetAsync(outn, 0, (size_t)kNT * 128 * 4, stream);
    hipLaunchKernelGGL(edge_logits, dim3(cdiv(kE1 * 16, 256)), blk, 0, stream,
                       ecp_s, ecp_d, kE1, kC, qP, kNC, p1cp, alpha, mEnc);
    hipLaunchKernelGGL(edge_logits, dim3(cdiv(kE2 * 16, 256)), blk, 0, stream,
                       epc_s, epc_d, kE2, kP, qC, 0, p1pc, alpha + (size_t)kE1 * 2, mEnc);
    hipLaunchKernelGGL(edge_expsum, dim3(cdiv(kE1, 256)), blk, 0, stream,
                       ecp_d, kE1, kNC, mEnc, alpha, sSum);
    hipLaunchKernelGGL(edge_expsum, dim3(cdiv(kE2, 256)), blk, 0, stream,
                       epc_d, kE2, 0, mEnc, alpha + (size_t)kE1 * 2, sSum);
    hipLaunchKernelGGL(edge_scatter, dim3(cdiv(kE1 * 16, 256)), blk, 0, stream,
                       ecp_s, ecp_d, kE1, vC, kNC, alpha, sSum, outn);
    hipLaunchKernelGGL(edge_scatter, dim3(cdiv(kE2 * 16, 256)), blk, 0, stream,
                       epc_s, epc_d, kE2, vP, 0, alpha + (size_t)kE1 * 2, sSum, outn);
    // mix (kqv region becomes dead here; hc/hp overlay it)
    hipLaunchKernelGGL((gemm128<1,1,1,0>), dim3(cdiv(kNC,128)), blk, 0, stream,
                       outn, ow1c, 128, ob1c, (void*)hc, kNC, xc, s1c);
    hipLaunchKernelGGL((gemm128<1,1,1,0>), dim3(cdiv(kNP,128)), blk, 0, stream,
                       outn + (size_t)kNC * 128, ow1p, 128, ob1p, (void*)hp, kNP, xp, s1p);

    // ================= layer 2 (only customer outputs matter -> pc edges only) =================
    hipLaunchKernelGGL(fold_k, dim3(384), dim3(128), 0, stream, w2p, b2p, a2pc, m2pc, wep, bep);
    hipLaunchKernelGGL((gemm128<0,0,0,1>), dim3(cdiv(kNP,128)), blk, 0, stream,
                       hp, wep + 0,   384, bep + 0,   (void*)kP2, kNP, nullF, nullF);
    hipLaunchKernelGGL((gemm128<0,0,0,1>), dim3(cdiv(kNP,128)), blk, 0, stream,
                       hp, wep + 256, 384, bep + 256, (void*)vP2, kNP, nullF, nullF);
    hipLaunchKernelGGL((gemm128<0,0,0,0>), dim3(cdiv(kNC,128)), blk, 0, stream,
                       hc, w2c + 128, 384, b2c + 128, (void*)qC2, kNC, nullF, nullF);
    hipMemsetAsync(mEnc, 0, (size_t)kNC * 2 * 4, stream);
    hipMemsetAsync(sSum, 0, (size_t)kNC * 2 * 4, stream);
    hipMemsetAsync(outn, 0, (size_t)kNC * 128 * 4, stream);
    hipLaunchKernelGGL(edge_logits, dim3(cdiv(kE2 * 16, 256)), blk, 0, stream,
                       epc_s, epc_d, kE2, kP2, qC2, 0, p2pc, alpha, mEnc);
    hipLaunchKernelGGL(edge_expsum, dim3(cdiv(kE2, 256)), blk, 0, stream,
                       epc_d, kE2, 0, mEnc, alpha, sSum);
    hipLaunchKernelGGL(edge_scatter, dim3(cdiv(kE2 * 16, 256)), blk, 0, stream,
                       epc_s, epc_d, kE2, vP2, 0, alpha, sSum, outn);
    hipLaunchKernelGGL((gemm128<1,1,0,0>), dim3(cdiv(kNC,128)), blk, 0, stream,
                       outn, ow2c, 128, ob2c, (void*)hc, kNC, hc, s2c);
    hipLaunchKernelGGL(final16, dim3(cdiv(kNC,64)), blk, 0, stream, hc, wl, bl, outF, kNC);
}

// Round 3
// 1007.482 us; speedup vs baseline: 4.2413x; 4.2413x over previous
//
#include <hip/hip_runtime.h>

typedef __attribute__((ext_vector_type(8))) unsigned short us8;

constexpr int kNC = 100000;
constexpr int kNP = 50000;
constexpr int kNT = kNC + kNP;
constexpr int kE1 = 300000;
constexpr int kE2 = 300000;
constexpr int kCAP = 32;   // max in-degree per node per edge type (Poisson(6) -> P(>=32)<1e-8)

__device__ __forceinline__ float geluf(float x) {
    return 0.5f * x * (1.0f + erff(x * 0.7071067811865475f));
}
__device__ __forceinline__ unsigned short f2bf(float f) {  // RTNE
    unsigned int u = __float_as_uint(f);
    u += 0x7fffu + ((u >> 16) & 1u);
    return (unsigned short)(u >> 16);
}
__device__ __forceinline__ float bf2f(unsigned short s) {
    return __uint_as_float(((unsigned int)s) << 16);
}

// weff[:,0:128] = w_k @ blockdiag(a); [:,128:256] = w_q; [:,256:384] = w_v @ blockdiag(m)
__global__ void fold_k(const float* __restrict__ w, const float* __restrict__ b,
                       const float* __restrict__ ar, const float* __restrict__ mr,
                       float* __restrict__ weff, float* __restrict__ beff) {
    int col = blockIdx.x;   // 0..383
    int i = threadIdx.x;    // 0..127
    float acc, bacc;
    if (col >= 128 && col < 256) {
        acc = w[i * 384 + col];
        bacc = b[col];
    } else {
        const float* rel = (col < 128) ? ar : mr;
        int base = (col < 128) ? 0 : 256;
        int c = col - base;
        int h = c >> 6, j = c & 63;
        acc = 0.0f; bacc = 0.0f;
        for (int d = 0; d < 64; ++d) {
            float rv = rel[(h * 64 + d) * 64 + j];
            acc  = fmaf(w[i * 384 + base + h * 64 + d], rv, acc);
            bacc = fmaf(b[base + h * 64 + d], rv, bacc);
        }
    }
    weff[i * 384 + col] = acc;
    if (i == 0) beff[col] = bacc;
}

// C[M,128] = op(A[M,128]) @ W[128 x 128 window] + bias.  K=128 fixed.
template<int PRO, int EPI, int RELU, int BF16OUT>
__global__ __launch_bounds__(256) void gemm128(
    const float* __restrict__ A,
    const float* __restrict__ W, int ldb,
    const float* __restrict__ bias,
    void* __restrict__ Cv,
    int M,
    const float* __restrict__ Xres,
    const float* __restrict__ sgate)
{
    __shared__ float As[128][132];   // [k][row], padded
    __shared__ float Ws[128][128];   // [k][col]
    const int t = threadIdx.x;
    const int row0 = blockIdx.x * 128;

    { // A tile transposed into LDS
        int rl = t & 31;
        int kh = t >> 5;  // 0..7
        #pragma unroll
        for (int ir = 0; ir < 4; ++ir) {
            int r = ir * 32 + rl;
            int gr = row0 + r;
            #pragma unroll
            for (int ic = 0; ic < 4; ++ic) {
                int k = (ic * 8 + kh) * 4;
                float4 v = make_float4(0.f, 0.f, 0.f, 0.f);
                if (gr < M) v = *(const float4*)(A + (size_t)gr * 128 + k);
                if (PRO) { v.x = geluf(v.x); v.y = geluf(v.y); v.z = geluf(v.z); v.w = geluf(v.w); }
                As[k + 0][r] = v.x;
                As[k + 1][r] = v.y;
                As[k + 2][r] = v.z;
                As[k + 3][r] = v.w;
            }
        }
    }
    { // W tile
        int c = (t & 31) * 4;
        int kh = t >> 5;
        #pragma unroll
        for (int i = 0; i < 16; ++i) {
            int k = i * 8 + kh;
            *(float4*)&Ws[k][c] = *(const float4*)(W + (size_t)k * ldb + c);
        }
    }
    __syncthreads();

    const int tx = t & 15, ty = t >> 4;
    float acc[8][8];
    #pragma unroll
    for (int j = 0; j < 8; ++j) {
        float bv = bias[tx * 8 + j];
        #pragma unroll
        for (int i = 0; i < 8; ++i) acc[i][j] = bv;
    }

    #pragma unroll 4
    for (int k = 0; k < 128; ++k) {
        float a[8], w[8];
        *(float4*)&a[0] = *(const float4*)&As[k][ty * 8 + 0];
        *(float4*)&a[4] = *(const float4*)&As[k][ty * 8 + 4];
        *(float4*)&w[0] = *(const float4*)&Ws[k][tx * 8 + 0];
        *(float4*)&w[4] = *(const float4*)&Ws[k][tx * 8 + 4];
        #pragma unroll
        for (int i = 0; i < 8; ++i)
            #pragma unroll
            for (int j = 0; j < 8; ++j)
                acc[i][j] = fmaf(a[i], w[j], acc[i][j]);
    }

    float g = 0.f, omg = 0.f;
    if (EPI == 1) { g = 1.0f / (1.0f + expf(-sgate[0])); omg = 1.0f - g; }

    #pragma unroll
    for (int i = 0; i < 8; ++i) {
        int gr = row0 + ty * 8 + i;
        if (gr >= M) continue;
        if (BF16OUT) {
            us8 o;
            #pragma unroll
            for (int j = 0; j < 8; ++j) o[j] = f2bf(acc[i][j]);
            *(us8*)((unsigned short*)Cv + (size_t)gr * 128 + tx * 8) = o;
        } else {
            float o[8];
            #pragma unroll
            for (int j = 0; j < 8; ++j) {
                float v = acc[i][j];
                if (EPI == 1) {
                    float xv = Xres[(size_t)gr * 128 + tx * 8 + j];
                    v = g * v + omg * xv;
                    if (RELU) v = fmaxf(v, 0.0f);
                }
                o[j] = v;
            }
            *(float4*)((float*)Cv + (size_t)gr * 128 + tx * 8 + 0) = *(float4*)&o[0];
            *(float4*)((float*)Cv + (size_t)gr * 128 + tx * 8 + 4) = *(float4*)&o[4];
        }
    }
}

// per edge: slot = cnt[dst]++; bucket[dst*CAP+slot] = src
__global__ __launch_bounds__(256) void build_bucket(
    const int* __restrict__ src, const int* __restrict__ dst, int E,
    int* __restrict__ cnt, int* __restrict__ bucket)
{
    int e = blockIdx.x * 256 + threadIdx.x;
    if (e >= E) return;
    int d = dst[e];
    int slot = atomicAdd(&cnt[d], 1);
    if (slot < kCAP) bucket[(size_t)d * kCAP + slot] = src[e];
}

// one wave per dst node. lane l owns row elements {2l, 2l+1}.
// lanes 0..31 = head 0 (elems 0..63), lanes 32..63 = head 1.
// qo: read q row, overwrite with attention output (same buffer).
__global__ __launch_bounds__(256) void fused_attn(
    int ndst, const int* __restrict__ cnt, const int* __restrict__ bucket,
    const unsigned short* __restrict__ kSrc, const unsigned short* __restrict__ vSrc,
    float* __restrict__ qo, const float* __restrict__ prel)
{
    int wid = (blockIdx.x * 256 + threadIdx.x) >> 6;
    int lane = threadIdx.x & 63;
    if (wid >= ndst) return;
    int deg = cnt[wid];
    if (deg > kCAP) deg = kCAP;
    int mys = (lane < deg) ? bucket[(size_t)wid * kCAP + lane] : 0;
    float2 q = *(const float2*)(qo + (size_t)wid * 128 + lane * 2);
    float ph = prel[lane >> 5] * 0.125f;   // / sqrt(64)
    float m = -3.4e38f, ss = 0.f, o0 = 0.f, o1 = 0.f;
    for (int i = 0; i < deg; ++i) {
        int s = __shfl(mys, i);
        unsigned int kk = *(const unsigned int*)(kSrc + (size_t)s * 128 + lane * 2);
        float p = q.x * bf2f((unsigned short)kk) + q.y * bf2f((unsigned short)(kk >> 16));
        p += __shfl_xor(p, 1);
        p += __shfl_xor(p, 2);
        p += __shfl_xor(p, 4);
        p += __shfl_xor(p, 8);
        p += __shfl_xor(p, 16);   // per-half (=per-head) sum
        float lg = p * ph;
        float mn = fmaxf(m, lg);
        float sc = __expf(m - mn);
        float w  = __expf(lg - mn);
        unsigned int vv = *(const unsigned int*)(vSrc + (size_t)s * 128 + lane * 2);
        ss = ss * sc + w;
        o0 = o0 * sc + w * bf2f((unsigned short)vv);
        o1 = o1 * sc + w * bf2f((unsigned short)(vv >> 16));
        m = mn;
    }
    float r = 1.0f / (ss + 1e-16f);
    *(float2*)(qo + (size_t)wid * 128 + lane * 2) = make_float2(o0 * r, o1 * r);
}

// out[M,16] = A[M,128] @ W[128,16] + bias
__global__ __launch_bounds__(256) void final16(
    const float* __restrict__ A, const float* __restrict__ W,
    const float* __restrict__ bias, float* __restrict__ out, int M)
{
    __shared__ float Ws[128 * 16];
    __shared__ float As[64][132];
    int t = threadIdx.x;
    int row0 = blockIdx.x * 64;
    for (int i = t * 4; i < 2048; i += 1024)
        *(float4*)&Ws[i] = *(const float4*)&W[i];
    {
        int rl = t >> 3;
        int cc = t & 7;
        for (int ir = 0; ir < 2; ++ir) {
            int r = ir * 32 + rl;
            int gr = row0 + r;
            for (int ic = 0; ic < 4; ++ic) {
                int c = (ic * 8 + cc) * 4;
                float4 v = make_float4(0.f, 0.f, 0.f, 0.f);
                if (gr < M) v = *(const float4*)(A + (size_t)gr * 128 + c);
                *(float4*)&As[r][c] = v;
            }
        }
    }
    __syncthreads();
    int r = t >> 2, q = t & 3;
    int gr = row0 + r;
    float acc[4];
    #pragma unroll
    for (int j = 0; j < 4; ++j) acc[j] = bias[q * 4 + j];
    for (int k = 0; k < 128; ++k) {
        float a = As[r][k];
        float4 w = *(const float4*)&Ws[k * 16 + q * 4];
        acc[0] = fmaf(a, w.x, acc[0]);
        acc[1] = fmaf(a, w.y, acc[1]);
        acc[2] = fmaf(a, w.z, acc[2]);
        acc[3] = fmaf(a, w.w, acc[3]);
    }
    if (gr < M) *(float4*)(out + (size_t)gr * 16 + q * 4) = *(float4*)&acc[0];
}

extern "C" void kernel_launch(void* const* d_in, const int* in_sizes, int n_in,
                              void* d_out, int out_size, void* d_ws, size_t ws_size,
                              hipStream_t stream)
{
    const float* xc  = (const float*)d_in[0];
    const float* xp  = (const float*)d_in[1];
    const float* w1c = (const float*)d_in[2];
    const float* b1c = (const float*)d_in[3];
    const float* w1p = (const float*)d_in[4];
    const float* b1p = (const float*)d_in[5];
    const float* a1cp= (const float*)d_in[6];
    const float* m1cp= (const float*)d_in[7];
    const float* p1cp= (const float*)d_in[8];
    const float* a1pc= (const float*)d_in[9];
    const float* m1pc= (const float*)d_in[10];
    const float* p1pc= (const float*)d_in[11];
    const float* ow1c= (const float*)d_in[12];
    const float* ob1c= (const float*)d_in[13];
    const float* ow1p= (const float*)d_in[14];
    const float* ob1p= (const float*)d_in[15];
    const float* s1c = (const float*)d_in[16];
    const float* s1p = (const float*)d_in[17];
    const float* w2c = (const float*)d_in[18];
    const float* b2c = (const float*)d_in[19];
    const float* w2p = (const float*)d_in[20];
    const float* b2p = (const float*)d_in[21];
    const float* a2pc= (const float*)d_in[25];
    const float* m2pc= (const float*)d_in[26];
    const float* p2pc= (const float*)d_in[27];
    const float* ow2c= (const float*)d_in[28];
    const float* ob2c= (const float*)d_in[29];
    const float* s2c = (const float*)d_in[32];
    const float* wl  = (const float*)d_in[34];
    const float* bl  = (const float*)d_in[35];
    const int* ecp_s = (const int*)d_in[36];
    const int* ecp_d = (const int*)d_in[37];
    const int* epc_s = (const int*)d_in[38];
    const int* epc_d = (const int*)d_in[39];
    float* outF = (float*)d_out;
    (void)in_sizes; (void)n_in; (void)out_size; (void)ws_size;

    // ---- workspace layout (~200 MB) ----
    char* ws = (char*)d_ws;
    size_t off = 0;
    auto take = [&](size_t bytes) { char* p = ws + off; off += (bytes + 255) & ~(size_t)255; return p; };
    // R0: kC+vC bf16 (L1) -> hc f32 (L1 mix .. end)
    char* R0 = take((size_t)kNC * 128 * 4);
    unsigned short* kC = (unsigned short*)R0;
    unsigned short* vC = (unsigned short*)(R0 + (size_t)kNC * 128 * 2);
    float* hc = (float*)R0;
    // R1: kP+vP bf16 (L1) -> kP2+vP2 bf16 (L2)
    char* R1 = take((size_t)kNP * 128 * 4);
    unsigned short* kP = (unsigned short*)R1;
    unsigned short* vP = (unsigned short*)(R1 + (size_t)kNP * 128 * 2);
    unsigned short* kP2 = kP;
    unsigned short* vP2 = vP;
    // R2: q/out f32 [NT][128]  (customers rows 0.., products rows kNC..)
    float* qAll = (float*)take((size_t)kNT * 128 * 4);
    float* qC = qAll;                       // also attention out for customers
    float* qP = qAll + (size_t)kNC * 128;   // also attention out for products
    // R3: hp f32
    float* hp = (float*)take((size_t)kNP * 128 * 4);
    // R4: buckets
    int* cntP = (int*)take((size_t)kNP * 4);
    int* cntC = (int*)take((size_t)kNC * 4);
    int* bucketP = (int*)take((size_t)kNP * kCAP * 4);  // cp edges: dst=product, stores customer src
    int* bucketC = (int*)take((size_t)kNC * kCAP * 4);  // pc edges: dst=customer, stores product src
    // R5: folded weights
    float* wec = (float*)take((size_t)128 * 384 * 4);
    float* bec = (float*)take((size_t)384 * 4);
    float* wep = (float*)take((size_t)128 * 384 * 4);
    float* bep = (float*)take((size_t)384 * 4);

    auto cdiv = [](int a, int b) { return (a + b - 1) / b; };
    dim3 blk(256);
    const float* nullF = nullptr;

    // bucket build (valid for both layers — same edge lists)
    hipMemsetAsync(cntP, 0, (size_t)kNP * 4, stream);
    hipMemsetAsync(cntC, 0, (size_t)kNC * 4, stream);
    hipLaunchKernelGGL(build_bucket, dim3(cdiv(kE1, 256)), blk, 0, stream, ecp_s, ecp_d, kE1, cntP, bucketP);
    hipLaunchKernelGGL(build_bucket, dim3(cdiv(kE2, 256)), blk, 0, stream, epc_s, epc_d, kE2, cntC, bucketC);

    // ================= layer 1 =================
    hipLaunchKernelGGL(fold_k, dim3(384), dim3(128), 0, stream, w1c, b1c, a1cp, m1cp, wec, bec);
    hipLaunchKernelGGL(fold_k, dim3(384), dim3(128), 0, stream, w1p, b1p, a1pc, m1pc, wep, bep);
    hipLaunchKernelGGL((gemm128<0,0,0,1>), dim3(cdiv(kNC,128)), blk, 0, stream,
                       xc, wec + 0,   384, bec + 0,   (void*)kC, kNC, nullF, nullF);
    hipLaunchKernelGGL((gemm128<0,0,0,0>), dim3(cdiv(kNC,128)), blk, 0, stream,
                       xc, wec + 128, 384, bec + 128, (void*)qC, kNC, nullF, nullF);
    hipLaunchKernelGGL((gemm128<0,0,0,1>), dim3(cdiv(kNC,128)), blk, 0, stream,
                       xc, wec + 256, 384, bec + 256, (void*)vC, kNC, nullF, nullF);
    hipLaunchKernelGGL((gemm128<0,0,0,1>), dim3(cdiv(kNP,128)), blk, 0, stream,
                       xp, wep + 0,   384, bep + 0,   (void*)kP, kNP, nullF, nullF);
    hipLaunchKernelGGL((gemm128<0,0,0,0>), dim3(cdiv(kNP,128)), blk, 0, stream,
                       xp, wep + 128, 384, bep + 128, (void*)qP, kNP, nullF, nullF);
    hipLaunchKernelGGL((gemm128<0,0,0,1>), dim3(cdiv(kNP,128)), blk, 0, stream,
                       xp, wep + 256, 384, bep + 256, (void*)vP, kNP, nullF, nullF);
    // fused segment attention (reads q, overwrites with out)
    hipLaunchKernelGGL(fused_attn, dim3(cdiv(kNP, 4)), blk, 0, stream,
                       kNP, cntP, bucketP, kC, vC, qP, p1cp);
    hipLaunchKernelGGL(fused_attn, dim3(cdiv(kNC, 4)), blk, 0, stream,
                       kNC, cntC, bucketC, kP, vP, qC, p1pc);
    // mix
    hipLaunchKernelGGL((gemm128<1,1,1,0>), dim3(cdiv(kNC,128)), blk, 0, stream,
                       qC, ow1c, 128, ob1c, (void*)hc, kNC, xc, s1c);
    hipLaunchKernelGGL((gemm128<1,1,1,0>), dim3(cdiv(kNP,128)), blk, 0, stream,
                       qP, ow1p, 128, ob1p, (void*)hp, kNP, xp, s1p);

    // ================= layer 2 (only customer outputs matter -> pc edges only) =================
    hipLaunchKernelGGL(fold_k, dim3(384), dim3(128), 0, stream, w2p, b2p, a2pc, m2pc, wep, bep);
    hipLaunchKernelGGL((gemm128<0,0,0,1>), dim3(cdiv(kNP,128)), blk, 0, stream,
                       hp, wep + 0,   384, bep + 0,   (void*)kP2, kNP, nullF, nullF);
    hipLaunchKernelGGL((gemm128<0,0,0,1>), dim3(cdiv(kNP,128)), blk, 0, stream,
                       hp, wep + 256, 384, bep + 256, (void*)vP2, kNP, nullF, nullF);
    hipLaunchKernelGGL((gemm128<0,0,0,0>), dim3(cdiv(kNC,128)), blk, 0, stream,
                       hc, w2c + 128, 384, b2c + 128, (void*)qC, kNC, nullF, nullF);
    hipLaunchKernelGGL(fused_attn, dim3(cdiv(kNC, 4)), blk, 0, stream,
                       kNC, cntC, bucketC, kP2, vP2, qC, p2pc);
    hipLaunchKernelGGL((gemm128<1,1,0,0>), dim3(cdiv(kNC,128)), blk, 0, stream,
                       qC, ow2c, 128, ob2c, (void*)hc, kNC, hc, s2c);
    hipLaunchKernelGGL(final16, dim3(cdiv(kNC,64)), blk, 0, stream, hc, wl, bl, outF, kNC);
}

// Round 4
// 791.063 us; speedup vs baseline: 5.4017x; 1.2736x over previous
//
#include <hip/hip_runtime.h>

typedef __attribute__((ext_vector_type(8))) unsigned short us8;

constexpr int kNC = 100000;
constexpr int kNP = 50000;
constexpr int kNT = kNC + kNP;
constexpr int kE1 = 300000;
constexpr int kE2 = 300000;
constexpr int kCAP = 32;   // max in-degree per node per edge type (Poisson(6) -> P(>=32)<1e-8)

__device__ __forceinline__ float geluf(float x) {
    return 0.5f * x * (1.0f + erff(x * 0.7071067811865475f));
}
__device__ __forceinline__ unsigned short f2bf(float f) {  // RTNE
    unsigned int u = __float_as_uint(f);
    u += 0x7fffu + ((u >> 16) & 1u);
    return (unsigned short)(u >> 16);
}
__device__ __forceinline__ float bf2f(unsigned short s) {
    return __uint_as_float(((unsigned int)s) << 16);
}

// weff[:,0:128] = w_k @ blockdiag(a); [:,128:256] = w_q; [:,256:384] = w_v @ blockdiag(m)
__global__ void fold_k(const float* __restrict__ w, const float* __restrict__ b,
                       const float* __restrict__ ar, const float* __restrict__ mr,
                       float* __restrict__ weff, float* __restrict__ beff) {
    int col = blockIdx.x;   // 0..383
    int i = threadIdx.x;    // 0..127
    float acc, bacc;
    if (col >= 128 && col < 256) {
        acc = w[i * 384 + col];
        bacc = b[col];
    } else {
        const float* rel = (col < 128) ? ar : mr;
        int base = (col < 128) ? 0 : 256;
        int c = col - base;
        int h = c >> 6, j = c & 63;
        acc = 0.0f; bacc = 0.0f;
        for (int d = 0; d < 64; ++d) {
            float rv = rel[(h * 64 + d) * 64 + j];
            acc  = fmaf(w[i * 384 + base + h * 64 + d], rv, acc);
            bacc = fmaf(b[base + h * 64 + d], rv, bacc);
        }
    }
    weff[i * 384 + col] = acc;
    if (i == 0) beff[col] = bacc;
}

struct Job {
    const float* W;      // 128-col window, row stride ldb
    const float* bias;   // 128 window
    void* out;           // f32 or bf16 [M,128]
    int bf16;
};

// C[M,128] = op(A[M,128]) @ J.W + J.bias, K=128 in 4 chunks of 32 (33.3 KB LDS -> 4 blocks/CU).
// blockIdx.y picks the job (fused k/q/v). PRO: gelu(A). EPI: g*o+(1-g)*Xres (+ReLU).
template<int PRO, int EPI, int RELU>
__global__ __launch_bounds__(256, 4) void gemm128(
    const float* __restrict__ A, int ldb,
    Job j0, Job j1, Job j2,
    int M,
    const float* __restrict__ Xres,
    const float* __restrict__ sgate)
{
    Job J = (blockIdx.y == 0) ? j0 : ((blockIdx.y == 1) ? j1 : j2);
    __shared__ float As[32][132];   // [k][row] transposed, padded
    __shared__ float Ws[32][128];   // [k][col]
    const int t = threadIdx.x;
    const int row0 = blockIdx.x * 128;
    const int tx = t & 15, ty = t >> 4;

    float acc[8][8];
    #pragma unroll
    for (int j = 0; j < 8; ++j) {
        float bv = J.bias[tx * 8 + j];
        #pragma unroll
        for (int i = 0; i < 8; ++i) acc[i][j] = bv;
    }

    for (int kc = 0; kc < 4; ++kc) {
        const int k0 = kc * 32;
        float4 av[4], wv[4];
        #pragma unroll
        for (int i = 0; i < 4; ++i) {   // A chunk: 128 rows x 32 k, coalesced per row
            int idx = i * 256 + t;
            int c = idx & 7, r = idx >> 3;
            int gr = row0 + r;
            float4 v = make_float4(0.f, 0.f, 0.f, 0.f);
            if (gr < M) v = *(const float4*)(A + (size_t)gr * 128 + k0 + c * 4);
            if (PRO) { v.x = geluf(v.x); v.y = geluf(v.y); v.z = geluf(v.z); v.w = geluf(v.w); }
            av[i] = v;
        }
        #pragma unroll
        for (int i = 0; i < 4; ++i) {   // W chunk: 32 k x 128 cols
            int idx = i * 256 + t;
            int kr = idx >> 5, c4 = idx & 31;
            wv[i] = *(const float4*)(J.W + (size_t)(k0 + kr) * ldb + c4 * 4);
        }
        if (kc) __syncthreads();        // previous chunk's compute done before overwrite
        #pragma unroll
        for (int i = 0; i < 4; ++i) {
            int idx = i * 256 + t;
            int c = idx & 7, r = idx >> 3;
            As[c * 4 + 0][r] = av[i].x;
            As[c * 4 + 1][r] = av[i].y;
            As[c * 4 + 2][r] = av[i].z;
            As[c * 4 + 3][r] = av[i].w;
            int kr = idx >> 5, c4 = idx & 31;
            *(float4*)&Ws[kr][c4 * 4] = wv[i];
        }
        __syncthreads();

        #pragma unroll 4
        for (int kk = 0; kk < 32; ++kk) {
            float a[8], w[8];
            *(float4*)&a[0] = *(const float4*)&As[kk][ty * 8 + 0];
            *(float4*)&a[4] = *(const float4*)&As[kk][ty * 8 + 4];
            *(float4*)&w[0] = *(const float4*)&Ws[kk][tx * 8 + 0];
            *(float4*)&w[4] = *(const float4*)&Ws[kk][tx * 8 + 4];
            #pragma unroll
            for (int i = 0; i < 8; ++i)
                #pragma unroll
                for (int j = 0; j < 8; ++j)
                    acc[i][j] = fmaf(a[i], w[j], acc[i][j]);
        }
    }

    float g = 0.f, omg = 0.f;
    if (EPI == 1) { g = 1.0f / (1.0f + expf(-sgate[0])); omg = 1.0f - g; }

    #pragma unroll
    for (int i = 0; i < 8; ++i) {
        int gr = row0 + ty * 8 + i;
        if (gr >= M) continue;
        if (J.bf16) {
            us8 o;
            #pragma unroll
            for (int j = 0; j < 8; ++j) o[j] = f2bf(acc[i][j]);
            *(us8*)((unsigned short*)J.out + (size_t)gr * 128 + tx * 8) = o;
        } else {
            float o[8];
            #pragma unroll
            for (int j = 0; j < 8; ++j) {
                float v = acc[i][j];
                if (EPI == 1) {
                    float xv = Xres[(size_t)gr * 128 + tx * 8 + j];
                    v = g * v + omg * xv;
                    if (RELU) v = fmaxf(v, 0.0f);
                }
                o[j] = v;
            }
            *(float4*)((float*)J.out + (size_t)gr * 128 + tx * 8 + 0) = *(float4*)&o[0];
            *(float4*)((float*)J.out + (size_t)gr * 128 + tx * 8 + 4) = *(float4*)&o[4];
        }
    }
}

// per edge: slot = cnt[dst]++; bucket[dst*CAP+slot] = src
__global__ __launch_bounds__(256) void build_bucket(
    const int* __restrict__ src, const int* __restrict__ dst, int E,
    int* __restrict__ cnt, int* __restrict__ bucket)
{
    int e = blockIdx.x * 256 + threadIdx.x;
    if (e >= E) return;
    int d = dst[e];
    int slot = atomicAdd(&cnt[d], 1);
    if (slot < kCAP) bucket[(size_t)d * kCAP + slot] = src[e];
}

// one wave per dst node. lane l owns row elements {2l, 2l+1}.
// lanes 0..31 = head 0 (elems 0..63), lanes 32..63 = head 1.
// qo: read q row, overwrite with attention output (same buffer).
__global__ __launch_bounds__(256) void fused_attn(
    int ndst, const int* __restrict__ cnt, const int* __restrict__ bucket,
    const unsigned short* __restrict__ kSrc, const unsigned short* __restrict__ vSrc,
    float* __restrict__ qo, const float* __restrict__ prel)
{
    int wid = (blockIdx.x * 256 + threadIdx.x) >> 6;
    int lane = threadIdx.x & 63;
    if (wid >= ndst) return;
    int deg = cnt[wid];
    if (deg > kCAP) deg = kCAP;
    int mys = (lane < deg) ? bucket[(size_t)wid * kCAP + lane] : 0;
    float2 q = *(const float2*)(qo + (size_t)wid * 128 + lane * 2);
    float ph = prel[lane >> 5] * 0.125f;   // / sqrt(64)
    float m = -3.4e38f, ss = 0.f, o0 = 0.f, o1 = 0.f;
    for (int i = 0; i < deg; ++i) {
        int s = __shfl(mys, i);
        unsigned int kk = *(const unsigned int*)(kSrc + (size_t)s * 128 + lane * 2);
        float p = q.x * bf2f((unsigned short)kk) + q.y * bf2f((unsigned short)(kk >> 16));
        p += __shfl_xor(p, 1);
        p += __shfl_xor(p, 2);
        p += __shfl_xor(p, 4);
        p += __shfl_xor(p, 8);
        p += __shfl_xor(p, 16);   // per-half (=per-head) sum
        float lg = p * ph;
        float mn = fmaxf(m, lg);
        float sc = __expf(m - mn);
        float w  = __expf(lg - mn);
        unsigned int vv = *(const unsigned int*)(vSrc + (size_t)s * 128 + lane * 2);
        ss = ss * sc + w;
        o0 = o0 * sc + w * bf2f((unsigned short)vv);
        o1 = o1 * sc + w * bf2f((unsigned short)(vv >> 16));
        m = mn;
    }
    float r = 1.0f / (ss + 1e-16f);
    *(float2*)(qo + (size_t)wid * 128 + lane * 2) = make_float2(o0 * r, o1 * r);
}

// out[M,16] = A[M,128] @ W[128,16] + bias
__global__ __launch_bounds__(256) void final16(
    const float* __restrict__ A, const float* __restrict__ W,
    const float* __restrict__ bias, float* __restrict__ out, int M)
{
    __shared__ float Ws[128 * 16];
    __shared__ float As[64][132];
    int t = threadIdx.x;
    int row0 = blockIdx.x * 64;
    for (int i = t * 4; i < 2048; i += 1024)
        *(float4*)&Ws[i] = *(const float4*)&W[i];
    {
        int rl = t >> 3;
        int cc = t & 7;
        for (int ir = 0; ir < 2; ++ir) {
            int r = ir * 32 + rl;
            int gr = row0 + r;
            for (int ic = 0; ic < 4; ++ic) {
                int c = (ic * 8 + cc) * 4;
                float4 v = make_float4(0.f, 0.f, 0.f, 0.f);
                if (gr < M) v = *(const float4*)(A + (size_t)gr * 128 + c);
                *(float4*)&As[r][c] = v;
            }
        }
    }
    __syncthreads();
    int r = t >> 2, q = t & 3;
    int gr = row0 + r;
    float acc[4];
    #pragma unroll
    for (int j = 0; j < 4; ++j) acc[j] = bias[q * 4 + j];
    for (int k = 0; k < 128; ++k) {
        float a = As[r][k];
        float4 w = *(const float4*)&Ws[k * 16 + q * 4];
        acc[0] = fmaf(a, w.x, acc[0]);
        acc[1] = fmaf(a, w.y, acc[1]);
        acc[2] = fmaf(a, w.z, acc[2]);
        acc[3] = fmaf(a, w.w, acc[3]);
    }
    if (gr < M) *(float4*)(out + (size_t)gr * 16 + q * 4) = *(float4*)&acc[0];
}

extern "C" void kernel_launch(void* const* d_in, const int* in_sizes, int n_in,
                              void* d_out, int out_size, void* d_ws, size_t ws_size,
                              hipStream_t stream)
{
    const float* xc  = (const float*)d_in[0];
    const float* xp  = (const float*)d_in[1];
    const float* w1c = (const float*)d_in[2];
    const float* b1c = (const float*)d_in[3];
    const float* w1p = (const float*)d_in[4];
    const float* b1p = (const float*)d_in[5];
    const float* a1cp= (const float*)d_in[6];
    const float* m1cp= (const float*)d_in[7];
    const float* p1cp= (const float*)d_in[8];
    const float* a1pc= (const float*)d_in[9];
    const float* m1pc= (const float*)d_in[10];
    const float* p1pc= (const float*)d_in[11];
    const float* ow1c= (const float*)d_in[12];
    const float* ob1c= (const float*)d_in[13];
    const float* ow1p= (const float*)d_in[14];
    const float* ob1p= (const float*)d_in[15];
    const float* s1c = (const float*)d_in[16];
    const float* s1p = (const float*)d_in[17];
    const float* w2c = (const float*)d_in[18];
    const float* b2c = (const float*)d_in[19];
    const float* w2p = (const float*)d_in[20];
    const float* b2p = (const float*)d_in[21];
    const float* a2pc= (const float*)d_in[25];
    const float* m2pc= (const float*)d_in[26];
    const float* p2pc= (const float*)d_in[27];
    const float* ow2c= (const float*)d_in[28];
    const float* ob2c= (const float*)d_in[29];
    const float* s2c = (const float*)d_in[32];
    const float* wl  = (const float*)d_in[34];
    const float* bl  = (const float*)d_in[35];
    const int* ecp_s = (const int*)d_in[36];
    const int* ecp_d = (const int*)d_in[37];
    const int* epc_s = (const int*)d_in[38];
    const int* epc_d = (const int*)d_in[39];
    float* outF = (float*)d_out;
    (void)in_sizes; (void)n_in; (void)out_size; (void)ws_size;

    // ---- workspace layout (~200 MB) ----
    char* ws = (char*)d_ws;
    size_t off = 0;
    auto take = [&](size_t bytes) { char* p = ws + off; off += (bytes + 255) & ~(size_t)255; return p; };
    // R0: kC+vC bf16 (L1) -> hc f32 (L1 mix .. end)
    char* R0 = take((size_t)kNC * 128 * 4);
    unsigned short* kC = (unsigned short*)R0;
    unsigned short* vC = (unsigned short*)(R0 + (size_t)kNC * 128 * 2);
    float* hc = (float*)R0;
    // R1: kP+vP bf16 (L1) -> kP2+vP2 bf16 (L2)
    char* R1 = take((size_t)kNP * 128 * 4);
    unsigned short* kP = (unsigned short*)R1;
    unsigned short* vP = (unsigned short*)(R1 + (size_t)kNP * 128 * 2);
    unsigned short* kP2 = kP;
    unsigned short* vP2 = vP;
    // R2: q/out f32 [NT][128]
    float* qAll = (float*)take((size_t)kNT * 128 * 4);
    float* qC = qAll;
    float* qP = qAll + (size_t)kNC * 128;
    // R3: hp f32
    float* hp = (float*)take((size_t)kNP * 128 * 4);
    // R4: buckets
    int* cntP = (int*)take((size_t)kNP * 4);
    int* cntC = (int*)take((size_t)kNC * 4);
    int* bucketP = (int*)take((size_t)kNP * kCAP * 4);
    int* bucketC = (int*)take((size_t)kNC * kCAP * 4);
    // R5: folded weights
    float* wec = (float*)take((size_t)128 * 384 * 4);
    float* bec = (float*)take((size_t)384 * 4);
    float* wep = (float*)take((size_t)128 * 384 * 4);
    float* bep = (float*)take((size_t)384 * 4);

    auto cdiv = [](int a, int b) { return (a + b - 1) / b; };
    dim3 blk(256);
    const float* nullF = nullptr;

    // bucket build (valid for both layers — same edge lists)
    hipMemsetAsync(cntP, 0, (size_t)kNP * 4, stream);
    hipMemsetAsync(cntC, 0, (size_t)kNC * 4, stream);
    hipLaunchKernelGGL(build_bucket, dim3(cdiv(kE1, 256)), blk, 0, stream, ecp_s, ecp_d, kE1, cntP, bucketP);
    hipLaunchKernelGGL(build_bucket, dim3(cdiv(kE2, 256)), blk, 0, stream, epc_s, epc_d, kE2, cntC, bucketC);

    // ================= layer 1 =================
    hipLaunchKernelGGL(fold_k, dim3(384), dim3(128), 0, stream, w1c, b1c, a1cp, m1cp, wec, bec);
    hipLaunchKernelGGL(fold_k, dim3(384), dim3(128), 0, stream, w1p, b1p, a1pc, m1pc, wep, bep);
    Job jkC = { wec + 0,   bec + 0,   (void*)kC, 1 };
    Job jqC = { wec + 128, bec + 128, (void*)qC, 0 };
    Job jvC = { wec + 256, bec + 256, (void*)vC, 1 };
    Job jkP = { wep + 0,   bep + 0,   (void*)kP, 1 };
    Job jqP = { wep + 128, bep + 128, (void*)qP, 0 };
    Job jvP = { wep + 256, bep + 256, (void*)vP, 1 };
    hipLaunchKernelGGL((gemm128<0,0,0>), dim3(cdiv(kNC,128), 3), blk, 0, stream,
                       xc, 384, jkC, jqC, jvC, kNC, nullF, nullF);
    hipLaunchKernelGGL((gemm128<0,0,0>), dim3(cdiv(kNP,128), 3), blk, 0, stream,
                       xp, 384, jkP, jqP, jvP, kNP, nullF, nullF);
    // fused segment attention (reads q, overwrites with out)
    hipLaunchKernelGGL(fused_attn, dim3(cdiv(kNP, 4)), blk, 0, stream,
                       kNP, cntP, bucketP, kC, vC, qP, p1cp);
    hipLaunchKernelGGL(fused_attn, dim3(cdiv(kNC, 4)), blk, 0, stream,
                       kNC, cntC, bucketC, kP, vP, qC, p1pc);
    // mix
    Job jmC = { ow1c, ob1c, (void*)hc, 0 };
    Job jmP = { ow1p, ob1p, (void*)hp, 0 };
    hipLaunchKernelGGL((gemm128<1,1,1>), dim3(cdiv(kNC,128), 1), blk, 0, stream,
                       qC, 128, jmC, jmC, jmC, kNC, xc, s1c);
    hipLaunchKernelGGL((gemm128<1,1,1>), dim3(cdiv(kNP,128), 1), blk, 0, stream,
                       qP, 128, jmP, jmP, jmP, kNP, xp, s1p);

    // ================= layer 2 (only customer outputs matter -> pc edges only) =================
    hipLaunchKernelGGL(fold_k, dim3(384), dim3(128), 0, stream, w2p, b2p, a2pc, m2pc, wep, bep);
    Job jkP2 = { wep + 0,   bep + 0,   (void*)kP2, 1 };
    Job jvP2 = { wep + 256, bep + 256, (void*)vP2, 1 };
    Job jqC2 = { w2c + 128, b2c + 128, (void*)qC,  0 };
    hipLaunchKernelGGL((gemm128<0,0,0>), dim3(cdiv(kNP,128), 2), blk, 0, stream,
                       hp, 384, jkP2, jvP2, jvP2, kNP, nullF, nullF);
    hipLaunchKernelGGL((gemm128<0,0,0>), dim3(cdiv(kNC,128), 1), blk, 0, stream,
                       hc, 384, jqC2, jqC2, jqC2, kNC, nullF, nullF);
    hipLaunchKernelGGL(fused_attn, dim3(cdiv(kNC, 4)), blk, 0, stream,
                       kNC, cntC, bucketC, kP2, vP2, qC, p2pc);
    Job jm2 = { ow2c, ob2c, (void*)hc, 0 };
    hipLaunchKernelGGL((gemm128<1,1,0>), dim3(cdiv(kNC,128), 1), blk, 0, stream,
                       qC, 128, jm2, jm2, jm2, kNC, hc, s2c);
    hipLaunchKernelGGL(final16, dim3(cdiv(kNC,64)), blk, 0, stream, hc, wl, bl, outF, kNC);
}

// Round 5
// 505.055 us; speedup vs baseline: 8.4606x; 1.5663x over previous
//
#include <hip/hip_runtime.h>

typedef __attribute__((ext_vector_type(8))) short s16x8;   // bf16x8 MFMA operand
typedef __attribute__((ext_vector_type(4))) float f32x4;   // MFMA accumulator

constexpr int kNC = 100000;
constexpr int kNP = 50000;
constexpr int kNT = kNC + kNP;
constexpr int kE1 = 300000;
constexpr int kE2 = 300000;
constexpr int kCAP = 32;   // max in-degree per node per edge type (Poisson(6) -> P(>=32)<1e-8)

__device__ __forceinline__ float geluf(float x) {
    return 0.5f * x * (1.0f + erff(x * 0.7071067811865475f));
}
__device__ __forceinline__ unsigned short f2bf(float f) {  // RTNE
    unsigned int u = __float_as_uint(f);
    u += 0x7fffu + ((u >> 16) & 1u);
    return (unsigned short)(u >> 16);
}
__device__ __forceinline__ float bf2f(unsigned short s) {
    return __uint_as_float(((unsigned int)s) << 16);
}

// weff[:,0:128] = w_k @ blockdiag(a); [:,128:256] = w_q; [:,256:384] = w_v @ blockdiag(m)
__global__ void fold_k(const float* __restrict__ w, const float* __restrict__ b,
                       const float* __restrict__ ar, const float* __restrict__ mr,
                       float* __restrict__ weff, float* __restrict__ beff) {
    int col = blockIdx.x;   // 0..383
    int i = threadIdx.x;    // 0..127
    float acc, bacc;
    if (col >= 128 && col < 256) {
        acc = w[i * 384 + col];
        bacc = b[col];
    } else {
        const float* rel = (col < 128) ? ar : mr;
        int base = (col < 128) ? 0 : 256;
        int c = col - base;
        int h = c >> 6, j = c & 63;
        acc = 0.0f; bacc = 0.0f;
        for (int d = 0; d < 64; ++d) {
            float rv = rel[(h * 64 + d) * 64 + j];
            acc  = fmaf(w[i * 384 + base + h * 64 + d], rv, acc);
            bacc = fmaf(b[base + h * 64 + d], rv, bacc);
        }
    }
    weff[i * 384 + col] = acc;
    if (i == 0) beff[col] = bacc;
}

struct Job {
    const float* W;      // 128-col window (pre-offset), row stride ldb
    const float* bias;   // pre-offset, 128 window
    void* out;           // f32 or bf16 [M,128]
    int bf16;
};

// C[M,128] = op(A[M,128]) @ J.W + J.bias via bf16 MFMA (f32 accumulate).
// A,W converted f32->bf16 during LDS staging. blockIdx.y picks job.
// PRO: gelu(A). EPI: g*o+(1-g)*Xres (+ReLU). 4 waves; wave w owns rows [w*32, w*32+32).
// Frag layout (gfx950 16x16x32): A/B lane&15 = row/col, k = (lane>>4)*4+(e&3)+16*(e>>2);
// C/D row=(lane>>4)*4+reg, col=lane&15.
template<int PRO, int EPI, int RELU>
__global__ __launch_bounds__(256) void gemm128(
    const float* __restrict__ A, int ldb,
    Job j0, Job j1, Job j2,
    int M,
    const float* __restrict__ Xres,
    const float* __restrict__ sgate)
{
    Job J = (blockIdx.y == 0) ? j0 : ((blockIdx.y == 1) ? j1 : j2);
    constexpr int LDE = 36;                    // padded stride (elems); 72B = 8B-aligned, <=2-way banks
    __shared__ unsigned short As[128 * LDE];   // [row][k] bf16
    __shared__ unsigned short Bs[128 * LDE];   // [col][k] bf16 (W transposed)
    const int t = threadIdx.x;
    const int lane = t & 63;
    const int w = t >> 6;
    const int l15 = lane & 15, l4 = lane >> 4;
    const int row0 = blockIdx.x * 128;

    f32x4 acc[2][8];
    #pragma unroll
    for (int n = 0; n < 8; ++n) {
        float bv = J.bias[n * 16 + l15];
        acc[0][n] = f32x4{bv, bv, bv, bv};
        acc[1][n] = acc[0][n];
    }

    for (int kc = 0; kc < 4; ++kc) {
        const int k0 = kc * 32;
        // stage A chunk: 128 rows x 32 k (coalesced float4 per row)
        float4 av[4];
        #pragma unroll
        for (int i = 0; i < 4; ++i) {
            int idx = i * 256 + t;
            int r = idx >> 3, kq = idx & 7;
            int gr = row0 + r;
            float4 v = make_float4(0.f, 0.f, 0.f, 0.f);
            if (gr < M) v = *(const float4*)(A + (size_t)gr * 128 + k0 + kq * 4);
            if (PRO) { v.x = geluf(v.x); v.y = geluf(v.y); v.z = geluf(v.z); v.w = geluf(v.w); }
            av[i] = v;
        }
        // stage W chunk: 32 k x 128 c (coalesced per k-row)
        float wv[4][4];
        #pragma unroll
        for (int i = 0; i < 4; ++i) {
            int idx = i * 256 + t;
            int c = idx & 127, kq = idx >> 7;
            #pragma unroll
            for (int k2 = 0; k2 < 4; ++k2)
                wv[i][k2] = J.W[(size_t)(k0 + kq * 4 + k2) * ldb + c];
        }
        if (kc) __syncthreads();   // frag reads of previous chunk complete
        #pragma unroll
        for (int i = 0; i < 4; ++i) {
            int idx = i * 256 + t;
            int r = idx >> 3, kq = idx & 7;
            uint2 pa;
            pa.x = (unsigned)f2bf(av[i].x) | ((unsigned)f2bf(av[i].y) << 16);
            pa.y = (unsigned)f2bf(av[i].z) | ((unsigned)f2bf(av[i].w) << 16);
            *(uint2*)&As[r * LDE + kq * 4] = pa;
            int c = idx & 127, kq2 = idx >> 7;
            uint2 pb;
            pb.x = (unsigned)f2bf(wv[i][0]) | ((unsigned)f2bf(wv[i][1]) << 16);
            pb.y = (unsigned)f2bf(wv[i][2]) | ((unsigned)f2bf(wv[i][3]) << 16);
            *(uint2*)&Bs[c * LDE + kq2 * 4] = pb;
        }
        __syncthreads();

        union FR { uint2 u[2]; s16x8 v; };
        FR af[2];
        #pragma unroll
        for (int m = 0; m < 2; ++m) {
            const unsigned short* p = &As[(w * 32 + m * 16 + l15) * LDE + l4 * 4];
            af[m].u[0] = *(const uint2*)p;        // k-half 0 (k0..k0+15 block)
            af[m].u[1] = *(const uint2*)(p + 16); // k-half 1
        }
        #pragma unroll
        for (int n = 0; n < 8; ++n) {
            const unsigned short* p = &Bs[(n * 16 + l15) * LDE + l4 * 4];
            FR bf;
            bf.u[0] = *(const uint2*)p;
            bf.u[1] = *(const uint2*)(p + 16);
            acc[0][n] = __builtin_amdgcn_mfma_f32_16x16x32_bf16(af[0].v, bf.v, acc[0][n], 0, 0, 0);
            acc[1][n] = __builtin_amdgcn_mfma_f32_16x16x32_bf16(af[1].v, bf.v, acc[1][n], 0, 0, 0);
        }
    }

    float g = 0.f, omg = 0.f;
    if (EPI == 1) { g = 1.0f / (1.0f + expf(-sgate[0])); omg = 1.0f - g; }

    #pragma unroll
    for (int m = 0; m < 2; ++m) {
        int rbase = row0 + w * 32 + m * 16 + l4 * 4;
        #pragma unroll
        for (int r = 0; r < 4; ++r) {
            int gr = rbase + r;
            if (gr >= M) continue;
            if (J.bf16) {
                #pragma unroll
                for (int n = 0; n < 8; ++n)
                    ((unsigned short*)J.out)[(size_t)gr * 128 + n * 16 + l15] = f2bf(acc[m][n][r]);
            } else {
                #pragma unroll
                for (int n = 0; n < 8; ++n) {
                    float v = acc[m][n][r];
                    if (EPI == 1) {
                        float xv = Xres[(size_t)gr * 128 + n * 16 + l15];
                        v = g * v + omg * xv;
                        if (RELU) v = fmaxf(v, 0.0f);
                    }
                    ((float*)J.out)[(size_t)gr * 128 + n * 16 + l15] = v;
                }
            }
        }
    }
}

// per edge: slot = cnt[dst]++; bucket[dst*CAP+slot] = src
__global__ __launch_bounds__(256) void build_bucket(
    const int* __restrict__ src, const int* __restrict__ dst, int E,
    int* __restrict__ cnt, int* __restrict__ bucket)
{
    int e = blockIdx.x * 256 + threadIdx.x;
    if (e >= E) return;
    int d = dst[e];
    int slot = atomicAdd(&cnt[d], 1);
    if (slot < kCAP) bucket[(size_t)d * kCAP + slot] = src[e];
}

// one wave per dst node. lane l owns row elements {2l, 2l+1}.
// lanes 0..31 = head 0 (elems 0..63), lanes 32..63 = head 1.
// qo: read q row, overwrite with attention output (same buffer).
__global__ __launch_bounds__(256) void fused_attn(
    int ndst, const int* __restrict__ cnt, const int* __restrict__ bucket,
    const unsigned short* __restrict__ kSrc, const unsigned short* __restrict__ vSrc,
    float* __restrict__ qo, const float* __restrict__ prel)
{
    int wid = (blockIdx.x * 256 + threadIdx.x) >> 6;
    int lane = threadIdx.x & 63;
    if (wid >= ndst) return;
    int deg = cnt[wid];
    if (deg > kCAP) deg = kCAP;
    int mys = (lane < deg) ? bucket[(size_t)wid * kCAP + lane] : 0;
    float2 q = *(const float2*)(qo + (size_t)wid * 128 + lane * 2);
    float ph = prel[lane >> 5] * 0.125f;   // / sqrt(64)
    float m = -3.4e38f, ss = 0.f, o0 = 0.f, o1 = 0.f;
    for (int i = 0; i < deg; ++i) {
        int s = __shfl(mys, i);
        unsigned int kk = *(const unsigned int*)(kSrc + (size_t)s * 128 + lane * 2);
        float p = q.x * bf2f((unsigned short)kk) + q.y * bf2f((unsigned short)(kk >> 16));
        p += __shfl_xor(p, 1);
        p += __shfl_xor(p, 2);
        p += __shfl_xor(p, 4);
        p += __shfl_xor(p, 8);
        p += __shfl_xor(p, 16);   // per-half (=per-head) sum
        float lg = p * ph;
        float mn = fmaxf(m, lg);
        float sc = __expf(m - mn);
        float w  = __expf(lg - mn);
        unsigned int vv = *(const unsigned int*)(vSrc + (size_t)s * 128 + lane * 2);
        ss = ss * sc + w;
        o0 = o0 * sc + w * bf2f((unsigned short)vv);
        o1 = o1 * sc + w * bf2f((unsigned short)(vv >> 16));
        m = mn;
    }
    float r = 1.0f / (ss + 1e-16f);
    *(float2*)(qo + (size_t)wid * 128 + lane * 2) = make_float2(o0 * r, o1 * r);
}

// out[M,16] = A[M,128] @ W[128,16] + bias
__global__ __launch_bounds__(256) void final16(
    const float* __restrict__ A, const float* __restrict__ W,
    const float* __restrict__ bias, float* __restrict__ out, int M)
{
    __shared__ float Ws[128 * 16];
    __shared__ float As[64][132];
    int t = threadIdx.x;
    int row0 = blockIdx.x * 64;
    for (int i = t * 4; i < 2048; i += 1024)
        *(float4*)&Ws[i] = *(const float4*)&W[i];
    {
        int rl = t >> 3;
        int cc = t & 7;
        for (int ir = 0; ir < 2; ++ir) {
            int r = ir * 32 + rl;
            int gr = row0 + r;
            for (int ic = 0; ic < 4; ++ic) {
                int c = (ic * 8 + cc) * 4;
                float4 v = make_float4(0.f, 0.f, 0.f, 0.f);
                if (gr < M) v = *(const float4*)(A + (size_t)gr * 128 + c);
                *(float4*)&As[r][c] = v;
            }
        }
    }
    __syncthreads();
    int r = t >> 2, q = t & 3;
    int gr = row0 + r;
    float acc[4];
    #pragma unroll
    for (int j = 0; j < 4; ++j) acc[j] = bias[q * 4 + j];
    for (int k = 0; k < 128; ++k) {
        float a = As[r][k];
        float4 w = *(const float4*)&Ws[k * 16 + q * 4];
        acc[0] = fmaf(a, w.x, acc[0]);
        acc[1] = fmaf(a, w.y, acc[1]);
        acc[2] = fmaf(a, w.z, acc[2]);
        acc[3] = fmaf(a, w.w, acc[3]);
    }
    if (gr < M) *(float4*)(out + (size_t)gr * 16 + q * 4) = *(float4*)&acc[0];
}

extern "C" void kernel_launch(void* const* d_in, const int* in_sizes, int n_in,
                              void* d_out, int out_size, void* d_ws, size_t ws_size,
                              hipStream_t stream)
{
    const float* xc  = (const float*)d_in[0];
    const float* xp  = (const float*)d_in[1];
    const float* w1c = (const float*)d_in[2];
    const float* b1c = (const float*)d_in[3];
    const float* w1p = (const float*)d_in[4];
    const float* b1p = (const float*)d_in[5];
    const float* a1cp= (const float*)d_in[6];
    const float* m1cp= (const float*)d_in[7];
    const float* p1cp= (const float*)d_in[8];
    const float* a1pc= (const float*)d_in[9];
    const float* m1pc= (const float*)d_in[10];
    const float* p1pc= (const float*)d_in[11];
    const float* ow1c= (const float*)d_in[12];
    const float* ob1c= (const float*)d_in[13];
    const float* ow1p= (const float*)d_in[14];
    const float* ob1p= (const float*)d_in[15];
    const float* s1c = (const float*)d_in[16];
    const float* s1p = (const float*)d_in[17];
    const float* w2c = (const float*)d_in[18];
    const float* b2c = (const float*)d_in[19];
    const float* w2p = (const float*)d_in[20];
    const float* b2p = (const float*)d_in[21];
    const float* a2pc= (const float*)d_in[25];
    const float* m2pc= (const float*)d_in[26];
    const float* p2pc= (const float*)d_in[27];
    const float* ow2c= (const float*)d_in[28];
    const float* ob2c= (const float*)d_in[29];
    const float* s2c = (const float*)d_in[32];
    const float* wl  = (const float*)d_in[34];
    const float* bl  = (const float*)d_in[35];
    const int* ecp_s = (const int*)d_in[36];
    const int* ecp_d = (const int*)d_in[37];
    const int* epc_s = (const int*)d_in[38];
    const int* epc_d = (const int*)d_in[39];
    float* outF = (float*)d_out;
    (void)in_sizes; (void)n_in; (void)out_size; (void)ws_size;

    // ---- workspace layout (~200 MB) ----
    char* ws = (char*)d_ws;
    size_t off = 0;
    auto take = [&](size_t bytes) { char* p = ws + off; off += (bytes + 255) & ~(size_t)255; return p; };
    // R0: kC+vC bf16 (L1) -> hc f32 (L1 mix .. end)
    char* R0 = take((size_t)kNC * 128 * 4);
    unsigned short* kC = (unsigned short*)R0;
    unsigned short* vC = (unsigned short*)(R0 + (size_t)kNC * 128 * 2);
    float* hc = (float*)R0;
    // R1: kP+vP bf16 (L1) -> kP2+vP2 bf16 (L2)
    char* R1 = take((size_t)kNP * 128 * 4);
    unsigned short* kP = (unsigned short*)R1;
    unsigned short* vP = (unsigned short*)(R1 + (size_t)kNP * 128 * 2);
    unsigned short* kP2 = kP;
    unsigned short* vP2 = vP;
    // R2: q/out f32 [NT][128]
    float* qAll = (float*)take((size_t)kNT * 128 * 4);
    float* qC = qAll;
    float* qP = qAll + (size_t)kNC * 128;
    // R3: hp f32
    float* hp = (float*)take((size_t)kNP * 128 * 4);
    // R4: buckets
    int* cntP = (int*)take((size_t)kNP * 4);
    int* cntC = (int*)take((size_t)kNC * 4);
    int* bucketP = (int*)take((size_t)kNP * kCAP * 4);
    int* bucketC = (int*)take((size_t)kNC * kCAP * 4);
    // R5: folded weights
    float* wec = (float*)take((size_t)128 * 384 * 4);
    float* bec = (float*)take((size_t)384 * 4);
    float* wep = (float*)take((size_t)128 * 384 * 4);
    float* bep = (float*)take((size_t)384 * 4);

    auto cdiv = [](int a, int b) { return (a + b - 1) / b; };
    dim3 blk(256);
    const float* nullF = nullptr;

    // bucket build (valid for both layers — same edge lists)
    hipMemsetAsync(cntP, 0, (size_t)kNP * 4, stream);
    hipMemsetAsync(cntC, 0, (size_t)kNC * 4, stream);
    hipLaunchKernelGGL(build_bucket, dim3(cdiv(kE1, 256)), blk, 0, stream, ecp_s, ecp_d, kE1, cntP, bucketP);
    hipLaunchKernelGGL(build_bucket, dim3(cdiv(kE2, 256)), blk, 0, stream, epc_s, epc_d, kE2, cntC, bucketC);

    // ================= layer 1 =================
    hipLaunchKernelGGL(fold_k, dim3(384), dim3(128), 0, stream, w1c, b1c, a1cp, m1cp, wec, bec);
    hipLaunchKernelGGL(fold_k, dim3(384), dim3(128), 0, stream, w1p, b1p, a1pc, m1pc, wep, bep);
    Job jkC = { wec + 0,   bec + 0,   (void*)kC, 1 };
    Job jqC = { wec + 128, bec + 128, (void*)qC, 0 };
    Job jvC = { wec + 256, bec + 256, (void*)vC, 1 };
    Job jkP = { wep + 0,   bep + 0,   (void*)kP, 1 };
    Job jqP = { wep + 128, bep + 128, (void*)qP, 0 };
    Job jvP = { wep + 256, bep + 256, (void*)vP, 1 };
    hipLaunchKernelGGL((gemm128<0,0,0>), dim3(cdiv(kNC,128), 3), blk, 0, stream,
                       xc, 384, jkC, jqC, jvC, kNC, nullF, nullF);
    hipLaunchKernelGGL((gemm128<0,0,0>), dim3(cdiv(kNP,128), 3), blk, 0, stream,
                       xp, 384, jkP, jqP, jvP, kNP, nullF, nullF);
    // fused segment attention (reads q, overwrites with out)
    hipLaunchKernelGGL(fused_attn, dim3(cdiv(kNP, 4)), blk, 0, stream,
                       kNP, cntP, bucketP, kC, vC, qP, p1cp);
    hipLaunchKernelGGL(fused_attn, dim3(cdiv(kNC, 4)), blk, 0, stream,
                       kNC, cntC, bucketC, kP, vP, qC, p1pc);
    // mix
    Job jmC = { ow1c, ob1c, (void*)hc, 0 };
    Job jmP = { ow1p, ob1p, (void*)hp, 0 };
    hipLaunchKernelGGL((gemm128<1,1,1>), dim3(cdiv(kNC,128), 1), blk, 0, stream,
                       qC, 128, jmC, jmC, jmC, kNC, xc, s1c);
    hipLaunchKernelGGL((gemm128<1,1,1>), dim3(cdiv(kNP,128), 1), blk, 0, stream,
                       qP, 128, jmP, jmP, jmP, kNP, xp, s1p);

    // ================= layer 2 (only customer outputs matter -> pc edges only) =================
    hipLaunchKernelGGL(fold_k, dim3(384), dim3(128), 0, stream, w2p, b2p, a2pc, m2pc, wep, bep);
    Job jkP2 = { wep + 0,   bep + 0,   (void*)kP2, 1 };
    Job jvP2 = { wep + 256, bep + 256, (void*)vP2, 1 };
    Job jqC2 = { w2c + 128, b2c + 128, (void*)qC,  0 };
    hipLaunchKernelGGL((gemm128<0,0,0>), dim3(cdiv(kNP,128), 2), blk, 0, stream,
                       hp, 384, jkP2, jvP2, jvP2, kNP, nullF, nullF);
    hipLaunchKernelGGL((gemm128<0,0,0>), dim3(cdiv(kNC,128), 1), blk, 0, stream,
                       hc, 384, jqC2, jqC2, jqC2, kNC, nullF, nullF);
    hipLaunchKernelGGL(fused_attn, dim3(cdiv(kNC, 4)), blk, 0, stream,
                       kNC, cntC, bucketC, kP2, vP2, qC, p2pc);
    Job jm2 = { ow2c, ob2c, (void*)hc, 0 };
    hipLaunchKernelGGL((gemm128<1,1,0>), dim3(cdiv(kNC,128), 1), blk, 0, stream,
                       qC, 128, jm2, jm2, jm2, kNC, hc, s2c);
    hipLaunchKernelGGL(final16, dim3(cdiv(kNC,64)), blk, 0, stream, hc, wl, bl, outF, kNC);
}

// Round 6
// 434.830 us; speedup vs baseline: 9.8269x; 1.1615x over previous
//
#include <hip/hip_runtime.h>

typedef __attribute__((ext_vector_type(8))) short s16x8;   // bf16x8 MFMA operand
typedef __attribute__((ext_vector_type(4))) float f32x4;   // MFMA accumulator

constexpr int kNC = 100000;
constexpr int kNP = 50000;
constexpr int kNT = kNC + kNP;
constexpr int kE1 = 300000;
constexpr int kE2 = 300000;
constexpr int kCAP = 32;   // max in-degree per node per edge type

__device__ __forceinline__ float geluf(float x) {
    return 0.5f * x * (1.0f + erff(x * 0.7071067811865475f));
}
__device__ __forceinline__ unsigned short f2bf(float f) {  // RTNE
    unsigned int u = __float_as_uint(f);
    u += 0x7fffu + ((u >> 16) & 1u);
    return (unsigned short)(u >> 16);
}
__device__ __forceinline__ float bf2f(unsigned short s) {
    return __uint_as_float(((unsigned int)s) << 16);
}

// weff[:,0:128] = w_k @ blockdiag(a); [:,128:256] = w_q; [:,256:384] = w_v @ blockdiag(m)
__global__ void fold_k(const float* __restrict__ w, const float* __restrict__ b,
                       const float* __restrict__ ar, const float* __restrict__ mr,
                       float* __restrict__ weff, float* __restrict__ beff) {
    int col = blockIdx.x;   // 0..383
    int i = threadIdx.x;    // 0..127
    float acc, bacc;
    if (col >= 128 && col < 256) {
        acc = w[i * 384 + col];
        bacc = b[col];
    } else {
        const float* rel = (col < 128) ? ar : mr;
        int base = (col < 128) ? 0 : 256;
        int c = col - base;
        int h = c >> 6, j = c & 63;
        acc = 0.0f; bacc = 0.0f;
        for (int d = 0; d < 64; ++d) {
            float rv = rel[(h * 64 + d) * 64 + j];
            acc  = fmaf(w[i * 384 + base + h * 64 + d], rv, acc);
            bacc = fmaf(b[base + h * 64 + d], rv, bacc);
        }
    }
    weff[i * 384 + col] = acc;
    if (i == 0) beff[col] = bacc;
}

struct Job {
    const float* W;      // 128-col window (pre-offset), row stride ldb
    const float* bias;   // pre-offset, 128 window
    const void* A;       // [M,128] f32 or bf16
    const float* Xres;   // residual (EPI)
    const float* sgate;  // gate scalar (EPI)
    void* out;           // [M,128] f32/bf16, or [M,16] f32 (FINAL)
    int M;
    int ldb;
    int abf16;
    int bf16out;
};

// C[M,128] = op(A) @ J.W + J.bias via bf16 MFMA. Per-job A/M/dtypes; blockIdx.y picks job.
// PRO: gelu(A). EPI: g*o+(1-g)*Xres (+RELU). FINAL: fused (.)@wl+bl -> J.out [M,16] f32.
// Frag layout (gfx950 16x16x32, HW-verified R4/R5): A/B lane&15=row/col, k=(lane>>4)*4+(e&3)+16*(e>>2);
// C/D row=(lane>>4)*4+reg, col=lane&15.
template<int PRO, int EPI, int RELU, int FINAL>
__global__ __launch_bounds__(256) void gemm128(
    Job j0, Job j1, Job j2, Job j3, Job j4, Job j5,
    const float* __restrict__ wl, const float* __restrict__ bl)
{
    Job J;
    switch (blockIdx.y) {
        case 0: J = j0; break;
        case 1: J = j1; break;
        case 2: J = j2; break;
        case 3: J = j3; break;
        case 4: J = j4; break;
        default: J = j5; break;
    }
    const int row0 = blockIdx.x * 128;
    if (row0 >= J.M) return;

    constexpr int LDE = 36;    // staging stride (bf16 elems)
    constexpr int LDP = 132;   // FINAL tile stride
    constexpr int NSM = FINAL ? (128 * LDP) : (2 * 128 * LDE);
    __shared__ unsigned short sm[NSM];
    unsigned short* As = sm;                   // [row][k]
    unsigned short* Bs = sm + 128 * LDE;       // [col][k]

    const int t = threadIdx.x;
    const int lane = t & 63;
    const int w = t >> 6;
    const int l15 = lane & 15, l4 = lane >> 4;
    const int M = J.M;

    f32x4 acc[2][8];
    #pragma unroll
    for (int n = 0; n < 8; ++n) {
        float bv = J.bias[n * 16 + l15];
        acc[0][n] = f32x4{bv, bv, bv, bv};
        acc[1][n] = acc[0][n];
    }

    for (int kc = 0; kc < 4; ++kc) {
        const int k0 = kc * 32;
        uint2 pa[4];
        #pragma unroll
        for (int i = 0; i < 4; ++i) {
            int idx = i * 256 + t;
            int r = idx >> 3, kq = idx & 7;
            int gr = row0 + r;
            if (J.abf16) {
                ushort4 rv = {0, 0, 0, 0};
                if (gr < M) rv = *(const ushort4*)((const unsigned short*)J.A + (size_t)gr * 128 + k0 + kq * 4);
                if (PRO) {
                    pa[i].x = (unsigned)f2bf(geluf(bf2f(rv.x))) | ((unsigned)f2bf(geluf(bf2f(rv.y))) << 16);
                    pa[i].y = (unsigned)f2bf(geluf(bf2f(rv.z))) | ((unsigned)f2bf(geluf(bf2f(rv.w))) << 16);
                } else {
                    pa[i].x = (unsigned)rv.x | ((unsigned)rv.y << 16);
                    pa[i].y = (unsigned)rv.z | ((unsigned)rv.w << 16);
                }
            } else {
                float4 v = make_float4(0.f, 0.f, 0.f, 0.f);
                if (gr < M) v = *(const float4*)((const float*)J.A + (size_t)gr * 128 + k0 + kq * 4);
                if (PRO) { v.x = geluf(v.x); v.y = geluf(v.y); v.z = geluf(v.z); v.w = geluf(v.w); }
                pa[i].x = (unsigned)f2bf(v.x) | ((unsigned)f2bf(v.y) << 16);
                pa[i].y = (unsigned)f2bf(v.z) | ((unsigned)f2bf(v.w) << 16);
            }
        }
        float wv[4][4];
        #pragma unroll
        for (int i = 0; i < 4; ++i) {
            int idx = i * 256 + t;
            int c = idx & 127, kq = idx >> 7;
            #pragma unroll
            for (int k2 = 0; k2 < 4; ++k2)
                wv[i][k2] = J.W[(size_t)(k0 + kq * 4 + k2) * J.ldb + c];
        }
        if (kc) __syncthreads();
        #pragma unroll
        for (int i = 0; i < 4; ++i) {
            int idx = i * 256 + t;
            int r = idx >> 3, kq = idx & 7;
            *(uint2*)&As[r * LDE + kq * 4] = pa[i];
            int c = idx & 127, kq2 = idx >> 7;
            uint2 pb;
            pb.x = (unsigned)f2bf(wv[i][0]) | ((unsigned)f2bf(wv[i][1]) << 16);
            pb.y = (unsigned)f2bf(wv[i][2]) | ((unsigned)f2bf(wv[i][3]) << 16);
            *(uint2*)&Bs[c * LDE + kq2 * 4] = pb;
        }
        __syncthreads();

        union FR { uint2 u[2]; s16x8 v; };
        FR af[2];
        #pragma unroll
        for (int m = 0; m < 2; ++m) {
            const unsigned short* p = &As[(w * 32 + m * 16 + l15) * LDE + l4 * 4];
            af[m].u[0] = *(const uint2*)p;
            af[m].u[1] = *(const uint2*)(p + 16);
        }
        #pragma unroll
        for (int n = 0; n < 8; ++n) {
            const unsigned short* p = &Bs[(n * 16 + l15) * LDE + l4 * 4];
            FR bfr;
            bfr.u[0] = *(const uint2*)p;
            bfr.u[1] = *(const uint2*)(p + 16);
            acc[0][n] = __builtin_amdgcn_mfma_f32_16x16x32_bf16(af[0].v, bfr.v, acc[0][n], 0, 0, 0);
            acc[1][n] = __builtin_amdgcn_mfma_f32_16x16x32_bf16(af[1].v, bfr.v, acc[1][n], 0, 0, 0);
        }
    }

    float g = 0.f, omg = 0.f;
    if (EPI == 1) { g = 1.0f / (1.0f + expf(-J.sgate[0])); omg = 1.0f - g; }

    if (FINAL) __syncthreads();   // all frag reads done before tile overwrites sm

    #pragma unroll
    for (int m = 0; m < 2; ++m) {
        #pragma unroll
        for (int r = 0; r < 4; ++r) {
            int lr = w * 32 + m * 16 + l4 * 4 + r;
            int gr = row0 + lr;
            bool ok = gr < M;
            #pragma unroll
            for (int n = 0; n < 8; ++n) {
                float v = acc[m][n][r];
                if (EPI == 1) {
                    float xv = ok ? J.Xres[(size_t)gr * 128 + n * 16 + l15] : 0.f;
                    v = g * v + omg * xv;
                    if (RELU) v = fmaxf(v, 0.0f);
                }
                if (FINAL) {
                    sm[lr * LDP + n * 16 + l15] = f2bf(v);
                } else if (ok) {
                    if (J.bf16out)
                        ((unsigned short*)J.out)[(size_t)gr * 128 + n * 16 + l15] = f2bf(v);
                    else
                        ((float*)J.out)[(size_t)gr * 128 + n * 16 + l15] = v;
                }
            }
        }
    }

    if (FINAL) {
        // per-wave: tile rows [w*32, w*32+32) @ wl[128,16] + bl  (same-wave LDS RAW; no barrier needed)
        union FR { uint2 u[2]; s16x8 v; };
        f32x4 facc[2];
        float bv = bl[l15];
        facc[0] = f32x4{bv, bv, bv, bv};
        facc[1] = facc[0];
        #pragma unroll
        for (int kc2 = 0; kc2 < 4; ++kc2) {
            FR bfr;
            #pragma unroll
            for (int h = 0; h < 2; ++h) {
                float f0 = wl[(size_t)(kc2 * 32 + h * 16 + l4 * 4 + 0) * 16 + l15];
                float f1 = wl[(size_t)(kc2 * 32 + h * 16 + l4 * 4 + 1) * 16 + l15];
                float f2 = wl[(size_t)(kc2 * 32 + h * 16 + l4 * 4 + 2) * 16 + l15];
                float f3 = wl[(size_t)(kc2 * 32 + h * 16 + l4 * 4 + 3) * 16 + l15];
                bfr.u[h].x = (unsigned)f2bf(f0) | ((unsigned)f2bf(f1) << 16);
                bfr.u[h].y = (unsigned)f2bf(f2) | ((unsigned)f2bf(f3) << 16);
            }
            #pragma unroll
            for (int m = 0; m < 2; ++m) {
                FR afr;
                const unsigned short* p = &sm[(w * 32 + m * 16 + l15) * LDP + kc2 * 32 + l4 * 4];
                afr.u[0] = *(const uint2*)p;
                afr.u[1] = *(const uint2*)(p + 16);
                facc[m] = __builtin_amdgcn_mfma_f32_16x16x32_bf16(afr.v, bfr.v, facc[m], 0, 0, 0);
            }
        }
        #pragma unroll
        for (int m = 0; m < 2; ++m) {
            #pragma unroll
            for (int r = 0; r < 4; ++r) {
                int gr = row0 + w * 32 + m * 16 + l4 * 4 + r;
                if (gr < M) ((float*)J.out)[(size_t)gr * 16 + l15] = facc[m][r];
            }
        }
    }
}

// per edge: slot = cnt[dst]++; bucket[dst*CAP+slot] = src
__global__ __launch_bounds__(256) void build_bucket(
    const int* __restrict__ src, const int* __restrict__ dst, int E,
    int* __restrict__ cnt, int* __restrict__ bucket)
{
    int e = blockIdx.x * 256 + threadIdx.x;
    if (e >= E) return;
    int d = dst[e];
    int slot = atomicAdd(&cnt[d], 1);
    if (slot < kCAP) bucket[(size_t)d * kCAP + slot] = src[e];
}

// one wave per dst node; two independent job sets (A then B) in one dispatch.
// lane l owns elems {2l,2l+1}; lanes 0..31 head0, 32..63 head1. q/k/v/out all bf16; softmax f32.
__global__ __launch_bounds__(256) void fused_attn2(
    int nA, const int* __restrict__ cntA, const int* __restrict__ bucketA,
    const unsigned short* __restrict__ kA, const unsigned short* __restrict__ vA,
    unsigned short* __restrict__ qoA, const float* __restrict__ prelA,
    int nB, const int* __restrict__ cntB, const int* __restrict__ bucketB,
    const unsigned short* __restrict__ kB, const unsigned short* __restrict__ vB,
    unsigned short* __restrict__ qoB, const float* __restrict__ prelB)
{
    int wid = (blockIdx.x * 256 + threadIdx.x) >> 6;
    int lane = threadIdx.x & 63;
    const int* cnt; const int* bucket; const unsigned short* ks; const unsigned short* vs;
    unsigned short* qo; const float* prel;
    if (wid < nA) {
        cnt = cntA; bucket = bucketA; ks = kA; vs = vA; qo = qoA; prel = prelA;
    } else {
        wid -= nA;
        if (wid >= nB) return;
        cnt = cntB; bucket = bucketB; ks = kB; vs = vB; qo = qoB; prel = prelB;
    }
    int deg = cnt[wid];
    if (deg > kCAP) deg = kCAP;
    int mys = (lane < deg) ? bucket[(size_t)wid * kCAP + lane] : 0;
    unsigned int qv = *(const unsigned int*)(qo + (size_t)wid * 128 + lane * 2);
    float qx = bf2f((unsigned short)qv), qy = bf2f((unsigned short)(qv >> 16));
    float ph = prel[lane >> 5] * 0.125f;   // / sqrt(64)
    float m = -3.4e38f, ss = 0.f, o0 = 0.f, o1 = 0.f;
    for (int i = 0; i < deg; ++i) {
        int s = __shfl(mys, i);
        unsigned int kk = *(const unsigned int*)(ks + (size_t)s * 128 + lane * 2);
        float p = qx * bf2f((unsigned short)kk) + qy * bf2f((unsigned short)(kk >> 16));
        p += __shfl_xor(p, 1);
        p += __shfl_xor(p, 2);
        p += __shfl_xor(p, 4);
        p += __shfl_xor(p, 8);
        p += __shfl_xor(p, 16);   // per-half (=per-head) sum
        float lg = p * ph;
        float mn = fmaxf(m, lg);
        float sc = __expf(m - mn);
        float wgt = __expf(lg - mn);
        unsigned int vv = *(const unsigned int*)(vs + (size_t)s * 128 + lane * 2);
        ss = ss * sc + wgt;
        o0 = o0 * sc + wgt * bf2f((unsigned short)vv);
        o1 = o1 * sc + wgt * bf2f((unsigned short)(vv >> 16));
        m = mn;
    }
    float r = 1.0f / (ss + 1e-16f);
    unsigned int ov = (unsigned)f2bf(o0 * r) | ((unsigned)f2bf(o1 * r) << 16);
    *(unsigned int*)(qo + (size_t)wid * 128 + lane * 2) = ov;
}

extern "C" void kernel_launch(void* const* d_in, const int* in_sizes, int n_in,
                              void* d_out, int out_size, void* d_ws, size_t ws_size,
                              hipStream_t stream)
{
    const float* xc  = (const float*)d_in[0];
    const float* xp  = (const float*)d_in[1];
    const float* w1c = (const float*)d_in[2];
    const float* b1c = (const float*)d_in[3];
    const float* w1p = (const float*)d_in[4];
    const float* b1p = (const float*)d_in[5];
    const float* a1cp= (const float*)d_in[6];
    const float* m1cp= (const float*)d_in[7];
    const float* p1cp= (const float*)d_in[8];
    const float* a1pc= (const float*)d_in[9];
    const float* m1pc= (const float*)d_in[10];
    const float* p1pc= (const float*)d_in[11];
    const float* ow1c= (const float*)d_in[12];
    const float* ob1c= (const float*)d_in[13];
    const float* ow1p= (const float*)d_in[14];
    const float* ob1p= (const float*)d_in[15];
    const float* s1c = (const float*)d_in[16];
    const float* s1p = (const float*)d_in[17];
    const float* w2c = (const float*)d_in[18];
    const float* b2c = (const float*)d_in[19];
    const float* w2p = (const float*)d_in[20];
    const float* b2p = (const float*)d_in[21];
    const float* a2pc= (const float*)d_in[25];
    const float* m2pc= (const float*)d_in[26];
    const float* p2pc= (const float*)d_in[27];
    const float* ow2c= (const float*)d_in[28];
    const float* ob2c= (const float*)d_in[29];
    const float* s2c = (const float*)d_in[32];
    const float* wl  = (const float*)d_in[34];
    const float* bl  = (const float*)d_in[35];
    const int* ecp_s = (const int*)d_in[36];
    const int* ecp_d = (const int*)d_in[37];
    const int* epc_s = (const int*)d_in[38];
    const int* epc_d = (const int*)d_in[39];
    float* outF = (float*)d_out;
    (void)in_sizes; (void)n_in; (void)out_size; (void)ws_size;

    // ---- workspace layout (~149 MB) ----
    char* ws = (char*)d_ws;
    size_t off = 0;
    auto take = [&](size_t bytes) { char* p = ws + off; off += (bytes + 255) & ~(size_t)255; return p; };
    // R0: kC+vC bf16 (L1) -> hc f32 (from M1 to end)
    char* R0 = take((size_t)kNC * 128 * 4);
    unsigned short* kC = (unsigned short*)R0;
    unsigned short* vC = (unsigned short*)(R0 + (size_t)kNC * 128 * 2);
    float* hc = (float*)R0;
    // R1: kP+vP bf16 (L1) -> kP2+vP2 bf16 (L2)
    char* R1 = take((size_t)kNP * 128 * 4);
    unsigned short* kP = (unsigned short*)R1;
    unsigned short* vP = (unsigned short*)(R1 + (size_t)kNP * 128 * 2);
    unsigned short* kP2 = kP;
    unsigned short* vP2 = vP;
    // R2: q/attn-out bf16 [NT][128]
    unsigned short* qAll = (unsigned short*)take((size_t)kNT * 128 * 2);
    unsigned short* qC = qAll;
    unsigned short* qP = qAll + (size_t)kNC * 128;
    // R3: hp bf16
    unsigned short* hp = (unsigned short*)take((size_t)kNP * 128 * 2);
    // R4: buckets
    int* cntP = (int*)take((size_t)kNP * 4);
    int* cntC = (int*)take((size_t)kNC * 4);
    int* bucketP = (int*)take((size_t)kNP * kCAP * 4);
    int* bucketC = (int*)take((size_t)kNC * kCAP * 4);
    // R5: folded weights
    float* wec = (float*)take((size_t)128 * 384 * 4);
    float* bec = (float*)take((size_t)384 * 4);
    float* wep = (float*)take((size_t)128 * 384 * 4);
    float* bep = (float*)take((size_t)384 * 4);

    auto cdiv = [](int a, int b) { return (a + b - 1) / b; };
    dim3 blk(256);
    const int gx = cdiv(kNC, 128);   // 782
    const float* nf = nullptr;

    // buckets (same edge lists both layers)
    hipMemsetAsync(cntP, 0, (size_t)kNP * 4, stream);
    hipMemsetAsync(cntC, 0, (size_t)kNC * 4, stream);
    hipLaunchKernelGGL(build_bucket, dim3(cdiv(kE1, 256)), blk, 0, stream, ecp_s, ecp_d, kE1, cntP, bucketP);
    hipLaunchKernelGGL(build_bucket, dim3(cdiv(kE2, 256)), blk, 0, stream, epc_s, epc_d, kE2, cntC, bucketC);

    // ================= layer 1 =================
    hipLaunchKernelGGL(fold_k, dim3(384), dim3(128), 0, stream, w1c, b1c, a1cp, m1cp, wec, bec);
    hipLaunchKernelGGL(fold_k, dim3(384), dim3(128), 0, stream, w1p, b1p, a1pc, m1pc, wep, bep);

    Job jkC = { wec + 0,   bec + 0,   xc, nf, nf, (void*)kC, kNC, 384, 0, 1 };
    Job jqC = { wec + 128, bec + 128, xc, nf, nf, (void*)qC, kNC, 384, 0, 1 };
    Job jvC = { wec + 256, bec + 256, xc, nf, nf, (void*)vC, kNC, 384, 0, 1 };
    Job jkP = { wep + 0,   bep + 0,   xp, nf, nf, (void*)kP, kNP, 384, 0, 1 };
    Job jqP = { wep + 128, bep + 128, xp, nf, nf, (void*)qP, kNP, 384, 0, 1 };
    Job jvP = { wep + 256, bep + 256, xp, nf, nf, (void*)vP, kNP, 384, 0, 1 };
    hipLaunchKernelGGL((gemm128<0,0,0,0>), dim3(gx, 6), blk, 0, stream,
                       jkC, jqC, jvC, jkP, jqP, jvP, nf, nf);

    // both L1 attentions in one dispatch (reads q bf16, overwrites with out bf16)
    hipLaunchKernelGGL(fused_attn2, dim3(cdiv(kNP + kNC, 4)), blk, 0, stream,
                       kNP, cntP, bucketP, kC, vC, qP, p1cp,
                       kNC, cntC, bucketC, kP, vP, qC, p1pc);

    Job jmC = { ow1c, ob1c, qC, xc, s1c, (void*)hc, kNC, 128, 1, 0 };
    Job jmP = { ow1p, ob1p, qP, xp, s1p, (void*)hp, kNP, 128, 1, 1 };
    hipLaunchKernelGGL((gemm128<1,1,1,0>), dim3(gx, 2), blk, 0, stream,
                       jmC, jmP, jmC, jmC, jmC, jmC, nf, nf);

    // ================= layer 2 (customer outputs only -> pc edges only) =================
    hipLaunchKernelGGL(fold_k, dim3(384), dim3(128), 0, stream, w2p, b2p, a2pc, m2pc, wep, bep);
    Job jk2 = { wep + 0,   bep + 0,   hp, nf, nf, (void*)kP2, kNP, 384, 1, 1 };
    Job jv2 = { wep + 256, bep + 256, hp, nf, nf, (void*)vP2, kNP, 384, 1, 1 };
    Job jq2 = { w2c + 128, b2c + 128, hc, nf, nf, (void*)qC,  kNC, 384, 0, 1 };
    hipLaunchKernelGGL((gemm128<0,0,0,0>), dim3(gx, 3), blk, 0, stream,
                       jk2, jv2, jq2, jk2, jk2, jk2, nf, nf);

    hipLaunchKernelGGL(fused_attn2, dim3(cdiv(kNC, 4)), blk, 0, stream,
                       kNC, cntC, bucketC, kP2, vP2, qC, p2pc,
                       0, cntC, bucketC, kP2, vP2, qC, p2pc);

    // mix2 + final projection fused: writes d_out [NC,16] directly
    Job jf = { ow2c, ob2c, qC, hc, s2c, (void*)outF, kNC, 128, 1, 0 };
    hipLaunchKernelGGL((gemm128<1,1,0,1>), dim3(gx, 1), blk, 0, stream,
                       jf, jf, jf, jf, jf, jf, wl, bl);
}